// Round 4
// baseline (408.621 us; speedup 1.0000x reference)
//
#include <hip/hip_runtime.h>

// VectorQuantizer: N=16384 rows, C=256, K=8192. inputs fp32, outputs fp32
// (z_q 4194304 ++ indices 16384 ++ loss 1). History: r12 (panel-coalesced B,
// 4 blk/CU) 374us / kMF 235us. r13 (launch_bounds 256,2 for bfA hoist)
// REFUTED: compiler sank the hoist anyway (VGPR 88, not 200) and occupancy
// halved -> 268us. Transaction accounting: tail exact_eval = 272 scattered
// lines/eval (256 of them stride-4KB hs reads) x ~800 evals/block => >90%
// of kMF's vector-mem transactions are the TAIL, not the screen.
// r14: 32-row blocks (grid 2048 = 512 rowBlk x 4 candSplit); after the
// screen, stage the block's 32 rows' fp32 hs data COALESCED into LDS
// (verbatim copy, union over the dead A-tile: 33.3KB -> still 4 blk/CU),
// tail reads f from LDS + e from emb only (~64 lines/eval, 4x fewer).
// Exact path unchanged: F is bit-verbatim hs, sequential-fmaf chain, u64
// key tie-break byte-identical to r9-r13.
//
// margin_n = 2e-5*sqrt(A_n) + 4e-5; flag iff R~ + margin >= rowRunningMax
// (monotone LDS atomicMax; stale threshold only over-flags => safe).
//
// Scratch in z_q float region of d_out (kZQ overwrites last); no d_ws.
// High-water 4,483,080 floats < r11-r13's proven-safe 4,514,832.

#define N_ROWS 16384
#define K_CAND 8192
#define CDIM   256
#define NELEM  4194304

#define SA_FLT   0          // A[16384] fp32 (numpy-pairwise-exact)
#define SK_FLT   16384      // keys u64[16384]
#define SL_FLT   49152      // lossAcc double
#define SQC_FLT  49160      // qcount u32[2048]
#define SBB_FLT  51208      // -B~ f32[8192]
#define SQ_FLT   59400      // queue u32[2048*624]
#define SFB_FLT  1337352    // fbf = bf16(2*f)[16384][256] as u16
#define SEB_FLT  3434504    // ebf2 = bf16(e) 16-cand panels (ends 4483080)
#define QCAP     624

typedef __attribute__((ext_vector_type(8))) short short8;
typedef __attribute__((ext_vector_type(4))) float f32x4;
typedef __attribute__((ext_vector_type(4))) unsigned uint32x4;

__device__ __forceinline__ unsigned short f2bf_rne(float x) {
    unsigned u = __float_as_uint(x);
    return (unsigned short)((u + 0x7fffu + ((u >> 16) & 1u)) >> 16);
}
__device__ __forceinline__ float bf2f(unsigned short u) {
    return __uint_as_float(((unsigned)u) << 16);
}
// monotone float->u32 map (handles negatives)
__device__ __forceinline__ unsigned ordU(float f) {
    unsigned u = __float_as_uint(f);
    return u ^ (((int)u >> 31) | 0x80000000u);
}

// exact ref-chain distance + key atomicMin (bit-identical to r6/r9 semantics)
__device__ __forceinline__ void exact_eval(const float* __restrict__ hs,
                                           const float* __restrict__ emb,
                                           const float* __restrict__ A,
                                           unsigned long long* keys,
                                           int row, int cand) {
    int b = row >> 10, yx = row & 1023;
    const float* fp = hs + ((size_t)b << 18) + yx;
    const float* ep = emb + ((size_t)cand << 8);
    float acc = 0.f;
    for (int c = 0; c < 256; ++c)
        acc = fmaf(fp[(size_t)c << 10], ep[c], acc);
    float d = __fsub_rn(A[row], __fadd_rn(acc, acc));
    unsigned long long key =
        ((unsigned long long)__float_as_uint(d) << 32) | (unsigned)cand;
    atomicMin(&keys[row], key);
}

// ---- kA: numpy-pairwise-exact A[n]; init keys + loss -----------------------
__global__ void kA(const float* __restrict__ hs, float* __restrict__ out) {
    float* A = out + SA_FLT;
    unsigned long long* keys = (unsigned long long*)(out + SK_FLT);
    int n = blockIdx.x * 256 + threadIdx.x;
    keys[n] = ~0ull;
    if (n == 0) *(double*)(out + SL_FLT) = 0.0;
    int b = n >> 10, yx = n & 1023;
    const float* base = hs + ((size_t)b << 18) + yx;
    float hsum[2];
    for (int h = 0; h < 2; ++h) {
        float r[8];
        #pragma unroll
        for (int j = 0; j < 8; ++j) {
            float x = base[(size_t)(h * 128 + j) << 10];
            r[j] = __fmul_rn(x, x);
        }
        for (int i = 8; i < 128; i += 8) {
            #pragma unroll
            for (int j = 0; j < 8; ++j) {
                float x = base[(size_t)(h * 128 + i + j) << 10];
                r[j] = __fadd_rn(r[j], __fmul_rn(x, x));
            }
        }
        hsum[h] = __fadd_rn(
            __fadd_rn(__fadd_rn(r[0], r[1]), __fadd_rn(r[2], r[3])),
            __fadd_rn(__fadd_rn(r[4], r[5]), __fadd_rn(r[6], r[7])));
    }
    A[n] = __fadd_rn(hsum[0], hsum[1]);
}

// ---- kFbf: (b,c,yx) -> bf16(2*f)[n][c] via LDS transpose -------------------
__global__ void kFbf(const float* __restrict__ hs, float* __restrict__ out) {
    unsigned short* fbf = (unsigned short*)(out + SFB_FLT);
    __shared__ float T[64][65];
    int blk = blockIdx.x;                 // 16 b x 4 cBlk x 16 yBlk = 1024
    int b = blk >> 6, cB = (blk >> 4) & 3, yB = blk & 15;
    int t = threadIdx.x;
    int yl = t & 63, ch = t >> 6;
    const float* src = hs + ((size_t)b << 18) + (((size_t)cB * 64) << 10) + yB * 64 + yl;
    #pragma unroll
    for (int i = 0; i < 16; ++i) {
        int c = ch * 16 + i;
        T[c][yl] = src[(size_t)c << 10];
    }
    __syncthreads();
    int yr = t >> 2, cs = (t & 3) * 16;
    short8 v0, v1;
    #pragma unroll
    for (int j = 0; j < 8; ++j) {
        v0[j] = (short)f2bf_rne(2.0f * T[cs + j][yr]);
        v1[j] = (short)f2bf_rne(2.0f * T[cs + 8 + j][yr]);
    }
    unsigned short* dst = fbf + (((size_t)(b * 1024 + yB * 64 + yr)) << 8) + cB * 64 + cs;
    *(short8*)dst = v0;
    *(short8*)(dst + 8) = v1;
}

// ---- kEbf: bf16(e) -> 16-cand panel layout + (-B~) -------------------------
// ebf2 layout (shorts): g=cand>>4, kc=c0/8 (0..31), cl=cand&15:
//   addr = g*4096 + kc*128 + cl*8   (panel 8KB, chunk row 256B, 16B/cand)
__global__ void kEbf(const float* __restrict__ emb, float* __restrict__ out) {
    unsigned short* ebf = (unsigned short*)(out + SEB_FLT);
    float* bbfNeg = out + SBB_FLT;
    int cand = blockIdx.x * 256 + threadIdx.x;   // grid 32
    const float* ep = emb + ((size_t)cand << 8);
    unsigned short* dp = ebf + (((size_t)(cand >> 4)) << 12) + (cand & 15) * 8;
    float s = 0.f;
    for (int c0 = 0; c0 < 256; c0 += 8) {
        short8 v;
        #pragma unroll
        for (int j = 0; j < 8; ++j) {
            unsigned short bb = f2bf_rne(ep[c0 + j]);
            v[j] = (short)bb;
            float eh = bf2f(bb);
            s = fmaf(eh, eh, s);
        }
        *(short8*)(dp + (c0 >> 3) * 128) = v;
    }
    bbfNeg[cand] = -s;
}

// ---- kMF: MFMA screen + flags + LDS-staged exact re-rank -------------------
// r14: 32-row blocks; LDS union {A-tile bf16 | fp32 row tile for tail}.
__global__ __launch_bounds__(256, 4) void kMF(const float* __restrict__ hs,
                                              const float* __restrict__ emb,
                                              float* __restrict__ out) {
    const float* A = out + SA_FLT;
    unsigned long long* keys = (unsigned long long*)(out + SK_FLT);
    unsigned* qcount = (unsigned*)(out + SQC_FLT);
    const float* bbfNeg = out + SBB_FLT;
    unsigned* queue = (unsigned*)(out + SQ_FLT);
    const unsigned short* fbf = (const unsigned short*)(out + SFB_FLT);
    const unsigned short* ebf = (const unsigned short*)(out + SEB_FLT);

    __shared__ __align__(16) union UU {
        short As[32][264];                // A-tile, stride 132 dw (16.9KB)
        float F[32][260];                 // fp32 row tile for tail (33.3KB)
    } U;
    __shared__ unsigned rowMaxOrd[32];
    __shared__ float margLds[32];
    __shared__ int lqn;

    const int t = threadIdx.x, blk = blockIdx.x;
    const int row0 = (blk >> 2) * 32;
    const int candSplit = (blk & 3) * 2048;
    const int lane = t & 63, wid = t >> 6;
    const int quad = lane >> 4, l15 = lane & 15;
    unsigned* qBlk = queue + (size_t)blk * QCAP;

    if (t < 32) {
        rowMaxOrd[t] = 0u;
        margLds[t] = 2.0e-5f * sqrtf(A[row0 + t]) + 4.0e-5f;
    }
    if (t == 0) lqn = 0;

    // stage A-tile ONCE: coalesced 16-B global loads, linear->2D LDS
    {
        const unsigned short* src = fbf + ((size_t)row0 << 8);
        #pragma unroll
        for (int i = 0; i < 4; ++i) {
            int idx = (i * 256 + t) * 8;          // linear short offset
            short8 v = *(const short8*)(src + idx);
            *(short8*)&U.As[idx >> 8][idx & 255] = v;
        }
    }
    __syncthreads();     // the ONLY barrier before the tail

    // loop-invariant margins -> registers
    f32x4 mgv[2];
    #pragma unroll
    for (int m = 0; m < 2; ++m)
        mgv[m] = *(const f32x4*)&margLds[m * 16 + quad * 4];

    for (int cc = 0; cc < 8; ++cc) {
        const int candW = candSplit + cc * 256 + wid * 64;
        // per-wave panel base: lanes (quad,l15) -> contiguous 1KB per (jc,ks)
        const unsigned short* ebW = ebf + (((size_t)candW) << 8)
                                       + quad * 128 + l15 * 8;
        short8 bfA[4][8];
        #pragma unroll
        for (int jc = 0; jc < 4; ++jc)
            #pragma unroll
            for (int ks = 0; ks < 8; ++ks)
                bfA[jc][ks] = *(const short8*)(ebW + jc * 4096 + ks * 512);

        f32x4 acc[2][4];
        #pragma unroll
        for (int jc = 0; jc < 4; ++jc) {
            float bneg = bbfNeg[candW + jc * 16 + l15];
            #pragma unroll
            for (int m = 0; m < 2; ++m)
                acc[m][jc] = (f32x4){bneg, bneg, bneg, bneg};
        }
        #pragma unroll
        for (int ks = 0; ks < 8; ++ks) {
            #pragma unroll
            for (int m = 0; m < 2; ++m) {
                short8 af = *(const short8*)&U.As[m * 16 + l15][ks * 32 + quad * 8];
                #pragma unroll
                for (int jc = 0; jc < 4; ++jc)
                    acc[m][jc] = __builtin_amdgcn_mfma_f32_16x16x32_bf16(
                        af, bfA[jc][ks], acc[m][jc], 0, 0, 0);
            }
        }
        // flag: per-(m,reg) early-out; ballot consensus so the 16-lane
        // shuffle-max never runs with inactive lanes (garbage-max hazard).
        #pragma unroll
        for (int m = 0; m < 2; ++m) {
            uint32x4 thv = *(const uint32x4*)&rowMaxOrd[m * 16 + quad * 4];
            #pragma unroll
            for (int reg = 0; reg < 4; ++reg) {
                int rl = m * 16 + quad * 4 + reg;
                float vmax = fmaxf(fmaxf(acc[m][0][reg], acc[m][1][reg]),
                                   fmaxf(acc[m][2][reg], acc[m][3][reg]));
                unsigned th = thv[reg];
                float mg = mgv[m][reg];
                bool hot = ordU(__fadd_rn(vmax, mg)) >= th;
                unsigned long long bal = __ballot(hot);
                if (((bal >> (quad * 16)) & 0xFFFFull) == 0ull) continue;
                float g = vmax;                       // all 16 lanes active
                g = fmaxf(g, __shfl_xor(g, 1, 16));
                g = fmaxf(g, __shfl_xor(g, 2, 16));
                g = fmaxf(g, __shfl_xor(g, 4, 16));
                g = fmaxf(g, __shfl_xor(g, 8, 16));
                unsigned og = ordU(g);
                if (og > th) { atomicMax(&rowMaxOrd[rl], og); th = og; }
                #pragma unroll
                for (int jc = 0; jc < 4; ++jc) {
                    float x = acc[m][jc][reg];
                    if (ordU(__fadd_rn(x, mg)) >= th) {
                        int slot = atomicAdd(&lqn, 1);
                        if (slot < QCAP)
                            qBlk[slot] = ((unsigned)rl << 13)
                                       | (unsigned)(candW + jc * 16 + l15);
                    }
                }
            }
        }
    }
    __syncthreads();                      // As dead for all waves after this
    if (t == 0) qcount[blk] = (unsigned)lqn;

    // stage block's 32 rows fp32 VERBATIM into LDS (coalesced: for fixed c,
    // 32 consecutive rows are contiguous in hs)
    {
        int yl = t & 31, cq = t >> 5;     // cq 0..7
        int nrow = row0 + yl;
        int b = nrow >> 10, yx = nrow & 1023;
        const float* src = hs + ((size_t)b << 18) + yx;
        #pragma unroll
        for (int i = 0; i < 32; ++i) {
            int c = i * 8 + cq;
            U.F[yl][c] = src[(size_t)c << 10];
        }
    }
    __syncthreads();

    int n = lqn; if (n > QCAP) n = QCAP;
    for (int i = t; i < n; i += 256) {
        unsigned e = qBlk[i];
        int rl = (int)(e >> 13), cand = (int)(e & 8191u);
        const float* ep = emb + ((size_t)cand << 8);
        float acc = 0.f;
        #pragma unroll 4
        for (int c0 = 0; c0 < 256; c0 += 4) {
            f32x4 f4 = *(const f32x4*)&U.F[rl][c0];   // LDS, exact hs copy
            f32x4 e4 = *(const f32x4*)(ep + c0);      // global fp32 emb
            acc = fmaf(f4[0], e4[0], acc);
            acc = fmaf(f4[1], e4[1], acc);
            acc = fmaf(f4[2], e4[2], acc);
            acc = fmaf(f4[3], e4[3], acc);
        }
        int row = row0 + rl;
        float d = __fsub_rn(A[row], __fadd_rn(acc, acc));
        unsigned long long key =
            ((unsigned long long)__float_as_uint(d) << 32) | (unsigned)cand;
        atomicMin(&keys[row], key);
    }
}

// ---- kFallback: exact full scan for overflowed blocks (normally no-op) -----
__global__ void kFallback(const float* __restrict__ hs, const float* __restrict__ emb,
                          float* __restrict__ out) {
    unsigned* qcount = (unsigned*)(out + SQC_FLT);
    if (qcount[blockIdx.x] <= QCAP) return;
    const float* A = out + SA_FLT;
    unsigned long long* keys = (unsigned long long*)(out + SK_FLT);
    int row0 = (int)(blockIdx.x >> 2) * 32, cb = (int)(blockIdx.x & 3) * 2048;
    for (int p = threadIdx.x; p < 32 * 2048; p += 256)
        exact_eval(hs, emb, A, keys, row0 + (p >> 11), cb + (p & 2047));
}

// ---- kPost / kLoss / kZQ (unchanged) ---------------------------------------
__global__ void kPost(float* __restrict__ out) {
    const unsigned long long* keys = (const unsigned long long*)(out + SK_FLT);
    double* lossAcc = (double*)(out + SL_FLT);
    __shared__ double sd[256];
    int n = blockIdx.x * 256 + threadIdx.x;
    unsigned long long key = keys[n];
    unsigned idx = (unsigned)(key & 0xffffffffu) & 8191u;
    float d = __uint_as_float((unsigned)(key >> 32));
    out[NELEM + n] = (float)idx;
    sd[threadIdx.x] = (double)d;
    __syncthreads();
    for (int s = 128; s > 0; s >>= 1) {
        if (threadIdx.x < s) sd[threadIdx.x] += sd[threadIdx.x + s];
        __syncthreads();
    }
    if (threadIdx.x == 0) atomicAdd(lossAcc, sd[0]);
}

__global__ void kLoss(float* __restrict__ out) {
    if (threadIdx.x == 0) {
        double loss = 1.25 * (*(const double*)(out + SL_FLT)) / (double)NELEM;
        out[NELEM + N_ROWS] = (float)loss;
    }
}

__global__ void kZQ(const float* __restrict__ hs, const float* __restrict__ emb,
                    float* __restrict__ out) {
    int o = blockIdx.x * 256 + threadIdx.x;
    int n = (o & 1023) | ((o >> 18) << 10);
    int c = (o >> 10) & 255;
    unsigned idx = (unsigned)out[NELEM + n] & 8191u;
    float e = emb[((size_t)idx << 8) + c];
    float h = hs[o];
    out[o] = __fadd_rn(h, __fsub_rn(e, h));
}

extern "C" void kernel_launch(void* const* d_in, const int* in_sizes, int n_in,
                              void* d_out, int out_size, void* d_ws, size_t ws_size,
                              hipStream_t stream) {
    const float* hs  = (const float*)d_in[0];
    const float* emb = (const float*)d_in[1];
    float* out = (float*)d_out;

    kA<<<N_ROWS / 256, 256, 0, stream>>>(hs, out);
    kFbf<<<1024, 256, 0, stream>>>(hs, out);
    kEbf<<<K_CAND / 256, 256, 0, stream>>>(emb, out);
    kMF<<<2048, 256, 0, stream>>>(hs, emb, out);
    kFallback<<<2048, 256, 0, stream>>>(hs, emb, out);
    kPost<<<N_ROWS / 256, 256, 0, stream>>>(out);
    kLoss<<<1, 64, 0, stream>>>(out);
    kZQ<<<NELEM / 256, 256, 0, stream>>>(hs, emb, out);
}

// Round 6
// 399.820 us; speedup vs baseline: 1.0220x; 1.0220x over previous
//
#include <hip/hip_runtime.h>

// VectorQuantizer: N=16384 rows, C=256, K=8192. inputs fp32, outputs fp32
// (z_q 4194304 ++ indices 16384 ++ loss 1).
// History: r12 (panel-coalesced B) 374us PASS. r14 (32-row blocks + LDS
// F-staged tail) 408us PASS but WRITE_SIZE 54.6MB (vs ~5MB real) = scratch
// spills from the source-level bfA[4][8] hoist vs the launch_bounds(256,4)
// 128-reg unified cap (VGPR_Count=64 = cap fingerprint). r13 proved the
// compiler sinks the hoist even with 256-reg budget -> hoist is pure loss.
// r15 (group-max u16 screen) FAILED indices: flagged vs GLOBAL max instead
// of r9-r14's candSplit-local stale running max -- unproven criterion,
// reverted wholesale.
// r16 = r14 VERBATIM minus the hoist: in-loop bf[4] panel loads (r12
// style). acc[2][4]=32 AGPR -> 96 VGPR budget for bf/af/addr/flags -> no
// spills. Every line from a passing kernel.
//
// margin_n = 2e-5*sqrt(A_n) + 4e-5; flag iff R~ + margin >= rowRunningMax
// (monotone LDS atomicMax, per candSplit block; stale threshold only
// over-flags => safe). Exact path: F verbatim hs copy in LDS, sequential
// fmaf chain, u64 key tie-break -- byte-identical to r9-r14.
//
// Scratch in z_q float region of d_out (kZQ overwrites last); no d_ws.
// High-water 4,483,080 floats (= r14's proven-safe envelope).

#define N_ROWS 16384
#define K_CAND 8192
#define CDIM   256
#define NELEM  4194304

#define SA_FLT   0          // A[16384] fp32 (numpy-pairwise-exact)
#define SK_FLT   16384      // keys u64[16384]
#define SL_FLT   49152      // lossAcc double
#define SQC_FLT  49160      // qcount u32[2048]
#define SBB_FLT  51208      // -B~ f32[8192]
#define SQ_FLT   59400      // queue u32[2048*624]
#define SFB_FLT  1337352    // fbf = bf16(2*f)[16384][256] as u16
#define SEB_FLT  3434504    // ebf2 = bf16(e) 16-cand panels (ends 4483080)
#define QCAP     624

typedef __attribute__((ext_vector_type(8))) short short8;
typedef __attribute__((ext_vector_type(4))) float f32x4;
typedef __attribute__((ext_vector_type(4))) unsigned uint32x4;

__device__ __forceinline__ unsigned short f2bf_rne(float x) {
    unsigned u = __float_as_uint(x);
    return (unsigned short)((u + 0x7fffu + ((u >> 16) & 1u)) >> 16);
}
__device__ __forceinline__ float bf2f(unsigned short u) {
    return __uint_as_float(((unsigned)u) << 16);
}
// monotone float->u32 map (handles negatives)
__device__ __forceinline__ unsigned ordU(float f) {
    unsigned u = __float_as_uint(f);
    return u ^ (((int)u >> 31) | 0x80000000u);
}

// exact ref-chain distance + key atomicMin (bit-identical to r6/r9 semantics)
__device__ __forceinline__ void exact_eval(const float* __restrict__ hs,
                                           const float* __restrict__ emb,
                                           const float* __restrict__ A,
                                           unsigned long long* keys,
                                           int row, int cand) {
    int b = row >> 10, yx = row & 1023;
    const float* fp = hs + ((size_t)b << 18) + yx;
    const float* ep = emb + ((size_t)cand << 8);
    float acc = 0.f;
    for (int c = 0; c < 256; ++c)
        acc = fmaf(fp[(size_t)c << 10], ep[c], acc);
    float d = __fsub_rn(A[row], __fadd_rn(acc, acc));
    unsigned long long key =
        ((unsigned long long)__float_as_uint(d) << 32) | (unsigned)cand;
    atomicMin(&keys[row], key);
}

// ---- kA: numpy-pairwise-exact A[n]; init keys + loss -----------------------
__global__ void kA(const float* __restrict__ hs, float* __restrict__ out) {
    float* A = out + SA_FLT;
    unsigned long long* keys = (unsigned long long*)(out + SK_FLT);
    int n = blockIdx.x * 256 + threadIdx.x;
    keys[n] = ~0ull;
    if (n == 0) *(double*)(out + SL_FLT) = 0.0;
    int b = n >> 10, yx = n & 1023;
    const float* base = hs + ((size_t)b << 18) + yx;
    float hsum[2];
    for (int h = 0; h < 2; ++h) {
        float r[8];
        #pragma unroll
        for (int j = 0; j < 8; ++j) {
            float x = base[(size_t)(h * 128 + j) << 10];
            r[j] = __fmul_rn(x, x);
        }
        for (int i = 8; i < 128; i += 8) {
            #pragma unroll
            for (int j = 0; j < 8; ++j) {
                float x = base[(size_t)(h * 128 + i + j) << 10];
                r[j] = __fadd_rn(r[j], __fmul_rn(x, x));
            }
        }
        hsum[h] = __fadd_rn(
            __fadd_rn(__fadd_rn(r[0], r[1]), __fadd_rn(r[2], r[3])),
            __fadd_rn(__fadd_rn(r[4], r[5]), __fadd_rn(r[6], r[7])));
    }
    A[n] = __fadd_rn(hsum[0], hsum[1]);
}

// ---- kFbf: (b,c,yx) -> bf16(2*f)[n][c] via LDS transpose -------------------
__global__ void kFbf(const float* __restrict__ hs, float* __restrict__ out) {
    unsigned short* fbf = (unsigned short*)(out + SFB_FLT);
    __shared__ float T[64][65];
    int blk = blockIdx.x;                 // 16 b x 4 cBlk x 16 yBlk = 1024
    int b = blk >> 6, cB = (blk >> 4) & 3, yB = blk & 15;
    int t = threadIdx.x;
    int yl = t & 63, ch = t >> 6;
    const float* src = hs + ((size_t)b << 18) + (((size_t)cB * 64) << 10) + yB * 64 + yl;
    #pragma unroll
    for (int i = 0; i < 16; ++i) {
        int c = ch * 16 + i;
        T[c][yl] = src[(size_t)c << 10];
    }
    __syncthreads();
    int yr = t >> 2, cs = (t & 3) * 16;
    short8 v0, v1;
    #pragma unroll
    for (int j = 0; j < 8; ++j) {
        v0[j] = (short)f2bf_rne(2.0f * T[cs + j][yr]);
        v1[j] = (short)f2bf_rne(2.0f * T[cs + 8 + j][yr]);
    }
    unsigned short* dst = fbf + (((size_t)(b * 1024 + yB * 64 + yr)) << 8) + cB * 64 + cs;
    *(short8*)dst = v0;
    *(short8*)(dst + 8) = v1;
}

// ---- kEbf: bf16(e) -> 16-cand panel layout + (-B~) -------------------------
// ebf2 layout (shorts): g=cand>>4, kc=c0/8 (0..31), cl=cand&15:
//   addr = g*4096 + kc*128 + cl*8   (panel 8KB, chunk row 256B, 16B/cand)
__global__ void kEbf(const float* __restrict__ emb, float* __restrict__ out) {
    unsigned short* ebf = (unsigned short*)(out + SEB_FLT);
    float* bbfNeg = out + SBB_FLT;
    int cand = blockIdx.x * 256 + threadIdx.x;   // grid 32
    const float* ep = emb + ((size_t)cand << 8);
    unsigned short* dp = ebf + (((size_t)(cand >> 4)) << 12) + (cand & 15) * 8;
    float s = 0.f;
    for (int c0 = 0; c0 < 256; c0 += 8) {
        short8 v;
        #pragma unroll
        for (int j = 0; j < 8; ++j) {
            unsigned short bb = f2bf_rne(ep[c0 + j]);
            v[j] = (short)bb;
            float eh = bf2f(bb);
            s = fmaf(eh, eh, s);
        }
        *(short8*)(dp + (c0 >> 3) * 128) = v;
    }
    bbfNeg[cand] = -s;
}

// ---- kMF: MFMA screen + flags + LDS-staged exact re-rank -------------------
// r16: 32-row blocks; in-loop bf[4] panel loads (NO source hoist); LDS union
// {A-tile bf16 | fp32 row tile for tail}.
__global__ __launch_bounds__(256, 4) void kMF(const float* __restrict__ hs,
                                              const float* __restrict__ emb,
                                              float* __restrict__ out) {
    const float* A = out + SA_FLT;
    unsigned long long* keys = (unsigned long long*)(out + SK_FLT);
    unsigned* qcount = (unsigned*)(out + SQC_FLT);
    const float* bbfNeg = out + SBB_FLT;
    unsigned* queue = (unsigned*)(out + SQ_FLT);
    const unsigned short* fbf = (const unsigned short*)(out + SFB_FLT);
    const unsigned short* ebf = (const unsigned short*)(out + SEB_FLT);

    __shared__ __align__(16) union UU {
        short As[32][264];                // A-tile, stride 132 dw (16.9KB)
        float F[32][260];                 // fp32 row tile for tail (33.3KB)
    } U;
    __shared__ unsigned rowMaxOrd[32];
    __shared__ float margLds[32];
    __shared__ int lqn;

    const int t = threadIdx.x, blk = blockIdx.x;
    const int row0 = (blk >> 2) * 32;
    const int candSplit = (blk & 3) * 2048;
    const int lane = t & 63, wid = t >> 6;
    const int quad = lane >> 4, l15 = lane & 15;
    unsigned* qBlk = queue + (size_t)blk * QCAP;

    if (t < 32) {
        rowMaxOrd[t] = 0u;
        margLds[t] = 2.0e-5f * sqrtf(A[row0 + t]) + 4.0e-5f;
    }
    if (t == 0) lqn = 0;

    // stage A-tile ONCE: coalesced 16-B global loads, linear->2D LDS
    {
        const unsigned short* src = fbf + ((size_t)row0 << 8);
        #pragma unroll
        for (int i = 0; i < 4; ++i) {
            int idx = (i * 256 + t) * 8;          // linear short offset
            short8 v = *(const short8*)(src + idx);
            *(short8*)&U.As[idx >> 8][idx & 255] = v;
        }
    }
    __syncthreads();     // the ONLY barrier before the tail

    // loop-invariant margins -> registers
    f32x4 mgv[2];
    #pragma unroll
    for (int m = 0; m < 2; ++m)
        mgv[m] = *(const f32x4*)&margLds[m * 16 + quad * 4];

    for (int cc = 0; cc < 8; ++cc) {
        const int candW = candSplit + cc * 256 + wid * 64;
        // per-wave panel base: lanes (quad,l15) -> contiguous 1KB per (jc,ks)
        const unsigned short* ebW = ebf + (((size_t)candW) << 8)
                                       + quad * 128 + l15 * 8;
        f32x4 acc[2][4];
        #pragma unroll
        for (int jc = 0; jc < 4; ++jc) {
            float bneg = bbfNeg[candW + jc * 16 + l15];
            #pragma unroll
            for (int m = 0; m < 2; ++m)
                acc[m][jc] = (f32x4){bneg, bneg, bneg, bneg};
        }
        #pragma unroll
        for (int ks = 0; ks < 8; ++ks) {
            short8 bf[4];
            #pragma unroll
            for (int jc = 0; jc < 4; ++jc)
                bf[jc] = *(const short8*)(ebW + jc * 4096 + ks * 512);
            #pragma unroll
            for (int m = 0; m < 2; ++m) {
                short8 af = *(const short8*)&U.As[m * 16 + l15][ks * 32 + quad * 8];
                #pragma unroll
                for (int jc = 0; jc < 4; ++jc)
                    acc[m][jc] = __builtin_amdgcn_mfma_f32_16x16x32_bf16(
                        af, bf[jc], acc[m][jc], 0, 0, 0);
            }
        }
        // flag: per-(m,reg) early-out; ballot consensus so the 16-lane
        // shuffle-max never runs with inactive lanes (garbage-max hazard).
        #pragma unroll
        for (int m = 0; m < 2; ++m) {
            uint32x4 thv = *(const uint32x4*)&rowMaxOrd[m * 16 + quad * 4];
            #pragma unroll
            for (int reg = 0; reg < 4; ++reg) {
                int rl = m * 16 + quad * 4 + reg;
                float vmax = fmaxf(fmaxf(acc[m][0][reg], acc[m][1][reg]),
                                   fmaxf(acc[m][2][reg], acc[m][3][reg]));
                unsigned th = thv[reg];
                float mg = mgv[m][reg];
                bool hot = ordU(__fadd_rn(vmax, mg)) >= th;
                unsigned long long bal = __ballot(hot);
                if (((bal >> (quad * 16)) & 0xFFFFull) == 0ull) continue;
                float g = vmax;                       // all 16 lanes active
                g = fmaxf(g, __shfl_xor(g, 1, 16));
                g = fmaxf(g, __shfl_xor(g, 2, 16));
                g = fmaxf(g, __shfl_xor(g, 4, 16));
                g = fmaxf(g, __shfl_xor(g, 8, 16));
                unsigned og = ordU(g);
                if (og > th) { atomicMax(&rowMaxOrd[rl], og); th = og; }
                #pragma unroll
                for (int jc = 0; jc < 4; ++jc) {
                    float x = acc[m][jc][reg];
                    if (ordU(__fadd_rn(x, mg)) >= th) {
                        int slot = atomicAdd(&lqn, 1);
                        if (slot < QCAP)
                            qBlk[slot] = ((unsigned)rl << 13)
                                       | (unsigned)(candW + jc * 16 + l15);
                    }
                }
            }
        }
    }
    __syncthreads();                      // As dead for all waves after this
    if (t == 0) qcount[blk] = (unsigned)lqn;

    // stage block's 32 rows fp32 VERBATIM into LDS (coalesced: for fixed c,
    // 32 consecutive rows are contiguous in hs)
    {
        int yl = t & 31, cq = t >> 5;     // cq 0..7
        int nrow = row0 + yl;
        int b = nrow >> 10, yx = nrow & 1023;
        const float* src = hs + ((size_t)b << 18) + yx;
        #pragma unroll
        for (int i = 0; i < 32; ++i) {
            int c = i * 8 + cq;
            U.F[yl][c] = src[(size_t)c << 10];
        }
    }
    __syncthreads();

    int n = lqn; if (n > QCAP) n = QCAP;
    for (int i = t; i < n; i += 256) {
        unsigned e = qBlk[i];
        int rl = (int)(e >> 13), cand = (int)(e & 8191u);
        const float* ep = emb + ((size_t)cand << 8);
        float acc = 0.f;
        #pragma unroll 4
        for (int c0 = 0; c0 < 256; c0 += 4) {
            f32x4 f4 = *(const f32x4*)&U.F[rl][c0];   // LDS, exact hs copy
            f32x4 e4 = *(const f32x4*)(ep + c0);      // global fp32 emb
            acc = fmaf(f4[0], e4[0], acc);
            acc = fmaf(f4[1], e4[1], acc);
            acc = fmaf(f4[2], e4[2], acc);
            acc = fmaf(f4[3], e4[3], acc);
        }
        int row = row0 + rl;
        float d = __fsub_rn(A[row], __fadd_rn(acc, acc));
        unsigned long long key =
            ((unsigned long long)__float_as_uint(d) << 32) | (unsigned)cand;
        atomicMin(&keys[row], key);
    }
}

// ---- kFallback: exact full scan for overflowed blocks (normally no-op) -----
__global__ void kFallback(const float* __restrict__ hs, const float* __restrict__ emb,
                          float* __restrict__ out) {
    unsigned* qcount = (unsigned*)(out + SQC_FLT);
    if (qcount[blockIdx.x] <= QCAP) return;
    const float* A = out + SA_FLT;
    unsigned long long* keys = (unsigned long long*)(out + SK_FLT);
    int row0 = (int)(blockIdx.x >> 2) * 32, cb = (int)(blockIdx.x & 3) * 2048;
    for (int p = threadIdx.x; p < 32 * 2048; p += 256)
        exact_eval(hs, emb, A, keys, row0 + (p >> 11), cb + (p & 2047));
}

// ---- kPost / kLoss / kZQ (unchanged) ---------------------------------------
__global__ void kPost(float* __restrict__ out) {
    const unsigned long long* keys = (const unsigned long long*)(out + SK_FLT);
    double* lossAcc = (double*)(out + SL_FLT);
    __shared__ double sd[256];
    int n = blockIdx.x * 256 + threadIdx.x;
    unsigned long long key = keys[n];
    unsigned idx = (unsigned)(key & 0xffffffffu) & 8191u;
    float d = __uint_as_float((unsigned)(key >> 32));
    out[NELEM + n] = (float)idx;
    sd[threadIdx.x] = (double)d;
    __syncthreads();
    for (int s = 128; s > 0; s >>= 1) {
        if (threadIdx.x < s) sd[threadIdx.x] += sd[threadIdx.x + s];
        __syncthreads();
    }
    if (threadIdx.x == 0) atomicAdd(lossAcc, sd[0]);
}

__global__ void kLoss(float* __restrict__ out) {
    if (threadIdx.x == 0) {
        double loss = 1.25 * (*(const double*)(out + SL_FLT)) / (double)NELEM;
        out[NELEM + N_ROWS] = (float)loss;
    }
}

__global__ void kZQ(const float* __restrict__ hs, const float* __restrict__ emb,
                    float* __restrict__ out) {
    int o = blockIdx.x * 256 + threadIdx.x;
    int n = (o & 1023) | ((o >> 18) << 10);
    int c = (o >> 10) & 255;
    unsigned idx = (unsigned)out[NELEM + n] & 8191u;
    float e = emb[((size_t)idx << 8) + c];
    float h = hs[o];
    out[o] = __fadd_rn(h, __fsub_rn(e, h));
}

extern "C" void kernel_launch(void* const* d_in, const int* in_sizes, int n_in,
                              void* d_out, int out_size, void* d_ws, size_t ws_size,
                              hipStream_t stream) {
    const float* hs  = (const float*)d_in[0];
    const float* emb = (const float*)d_in[1];
    float* out = (float*)d_out;

    kA<<<N_ROWS / 256, 256, 0, stream>>>(hs, out);
    kFbf<<<1024, 256, 0, stream>>>(hs, out);
    kEbf<<<K_CAND / 256, 256, 0, stream>>>(emb, out);
    kMF<<<2048, 256, 0, stream>>>(hs, emb, out);
    kFallback<<<2048, 256, 0, stream>>>(hs, emb, out);
    kPost<<<N_ROWS / 256, 256, 0, stream>>>(out);
    kLoss<<<1, 64, 0, stream>>>(out);
    kZQ<<<NELEM / 256, 256, 0, stream>>>(hs, emb, out);
}

// Round 7
// 379.502 us; speedup vs baseline: 1.0767x; 1.0535x over previous
//
#include <hip/hip_runtime.h>

// VectorQuantizer: N=16384 rows, C=256, K=8192. inputs fp32, outputs fp32
// (z_q 4194304 ++ indices 16384 ++ loss 1).
// History: r12 (panel-coalesced B, fused kMF) 374us PASS / kMF 235us.
// r14/r16 (32-row blocks + LDS F tail, de-hoisted) 400us PASS / kMF 251us.
// Knob-turn predictions failed 3x (occupancy, reg-budget, spill); WRITE_SIZE
// 46MB unexplained. r17: ABLATION ROUND -- split kMF at its existing tail
// barrier into kScr (screen+flag+queue, criterion byte-identical) and kTailE
// (F-staging + eval, verbatim, same 2048-block mapping, queue via global).
// Zero new logic; next round's counters attribute screen vs tail cost and
// localize the 46MB writes. One knob: kScr launch_bounds(256,3) (LDS now
// 17KB, reg cap 170) tests compiler auto-pipelining with reg headroom.
//
// margin_n = 2e-5*sqrt(A_n) + 4e-5; flag iff R~ + margin >= rowRunningMax
// (monotone LDS atomicMax, per candSplit block; stale threshold only
// over-flags => safe). Exact path: F verbatim hs copy in LDS, sequential
// fmaf chain, u64 key tie-break -- byte-identical to r9-r16.
//
// Scratch in z_q float region of d_out (kZQ overwrites last); no d_ws.
// High-water 4,483,080 floats (= r14/r16's proven-safe envelope).

#define N_ROWS 16384
#define K_CAND 8192
#define CDIM   256
#define NELEM  4194304

#define SA_FLT   0          // A[16384] fp32 (numpy-pairwise-exact)
#define SK_FLT   16384      // keys u64[16384]
#define SL_FLT   49152      // lossAcc double
#define SQC_FLT  49160      // qcount u32[2048]
#define SBB_FLT  51208      // -B~ f32[8192]
#define SQ_FLT   59400      // queue u32[2048*624]
#define SFB_FLT  1337352    // fbf = bf16(2*f)[16384][256] as u16
#define SEB_FLT  3434504    // ebf2 = bf16(e) 16-cand panels (ends 4483080)
#define QCAP     624

typedef __attribute__((ext_vector_type(8))) short short8;
typedef __attribute__((ext_vector_type(4))) float f32x4;
typedef __attribute__((ext_vector_type(4))) unsigned uint32x4;

__device__ __forceinline__ unsigned short f2bf_rne(float x) {
    unsigned u = __float_as_uint(x);
    return (unsigned short)((u + 0x7fffu + ((u >> 16) & 1u)) >> 16);
}
__device__ __forceinline__ float bf2f(unsigned short u) {
    return __uint_as_float(((unsigned)u) << 16);
}
// monotone float->u32 map (handles negatives)
__device__ __forceinline__ unsigned ordU(float f) {
    unsigned u = __float_as_uint(f);
    return u ^ (((int)u >> 31) | 0x80000000u);
}

// exact ref-chain distance + key atomicMin (bit-identical to r6/r9 semantics)
__device__ __forceinline__ void exact_eval(const float* __restrict__ hs,
                                           const float* __restrict__ emb,
                                           const float* __restrict__ A,
                                           unsigned long long* keys,
                                           int row, int cand) {
    int b = row >> 10, yx = row & 1023;
    const float* fp = hs + ((size_t)b << 18) + yx;
    const float* ep = emb + ((size_t)cand << 8);
    float acc = 0.f;
    for (int c = 0; c < 256; ++c)
        acc = fmaf(fp[(size_t)c << 10], ep[c], acc);
    float d = __fsub_rn(A[row], __fadd_rn(acc, acc));
    unsigned long long key =
        ((unsigned long long)__float_as_uint(d) << 32) | (unsigned)cand;
    atomicMin(&keys[row], key);
}

// ---- kA: numpy-pairwise-exact A[n]; init keys + loss -----------------------
__global__ void kA(const float* __restrict__ hs, float* __restrict__ out) {
    float* A = out + SA_FLT;
    unsigned long long* keys = (unsigned long long*)(out + SK_FLT);
    int n = blockIdx.x * 256 + threadIdx.x;
    keys[n] = ~0ull;
    if (n == 0) *(double*)(out + SL_FLT) = 0.0;
    int b = n >> 10, yx = n & 1023;
    const float* base = hs + ((size_t)b << 18) + yx;
    float hsum[2];
    for (int h = 0; h < 2; ++h) {
        float r[8];
        #pragma unroll
        for (int j = 0; j < 8; ++j) {
            float x = base[(size_t)(h * 128 + j) << 10];
            r[j] = __fmul_rn(x, x);
        }
        for (int i = 8; i < 128; i += 8) {
            #pragma unroll
            for (int j = 0; j < 8; ++j) {
                float x = base[(size_t)(h * 128 + i + j) << 10];
                r[j] = __fadd_rn(r[j], __fmul_rn(x, x));
            }
        }
        hsum[h] = __fadd_rn(
            __fadd_rn(__fadd_rn(r[0], r[1]), __fadd_rn(r[2], r[3])),
            __fadd_rn(__fadd_rn(r[4], r[5]), __fadd_rn(r[6], r[7])));
    }
    A[n] = __fadd_rn(hsum[0], hsum[1]);
}

// ---- kFbf: (b,c,yx) -> bf16(2*f)[n][c] via LDS transpose -------------------
__global__ void kFbf(const float* __restrict__ hs, float* __restrict__ out) {
    unsigned short* fbf = (unsigned short*)(out + SFB_FLT);
    __shared__ float T[64][65];
    int blk = blockIdx.x;                 // 16 b x 4 cBlk x 16 yBlk = 1024
    int b = blk >> 6, cB = (blk >> 4) & 3, yB = blk & 15;
    int t = threadIdx.x;
    int yl = t & 63, ch = t >> 6;
    const float* src = hs + ((size_t)b << 18) + (((size_t)cB * 64) << 10) + yB * 64 + yl;
    #pragma unroll
    for (int i = 0; i < 16; ++i) {
        int c = ch * 16 + i;
        T[c][yl] = src[(size_t)c << 10];
    }
    __syncthreads();
    int yr = t >> 2, cs = (t & 3) * 16;
    short8 v0, v1;
    #pragma unroll
    for (int j = 0; j < 8; ++j) {
        v0[j] = (short)f2bf_rne(2.0f * T[cs + j][yr]);
        v1[j] = (short)f2bf_rne(2.0f * T[cs + 8 + j][yr]);
    }
    unsigned short* dst = fbf + (((size_t)(b * 1024 + yB * 64 + yr)) << 8) + cB * 64 + cs;
    *(short8*)dst = v0;
    *(short8*)(dst + 8) = v1;
}

// ---- kEbf: bf16(e) -> 16-cand panel layout + (-B~) -------------------------
// ebf2 layout (shorts): g=cand>>4, kc=c0/8 (0..31), cl=cand&15:
//   addr = g*4096 + kc*128 + cl*8   (panel 8KB, chunk row 256B, 16B/cand)
__global__ void kEbf(const float* __restrict__ emb, float* __restrict__ out) {
    unsigned short* ebf = (unsigned short*)(out + SEB_FLT);
    float* bbfNeg = out + SBB_FLT;
    int cand = blockIdx.x * 256 + threadIdx.x;   // grid 32
    const float* ep = emb + ((size_t)cand << 8);
    unsigned short* dp = ebf + (((size_t)(cand >> 4)) << 12) + (cand & 15) * 8;
    float s = 0.f;
    for (int c0 = 0; c0 < 256; c0 += 8) {
        short8 v;
        #pragma unroll
        for (int j = 0; j < 8; ++j) {
            unsigned short bb = f2bf_rne(ep[c0 + j]);
            v[j] = (short)bb;
            float eh = bf2f(bb);
            s = fmaf(eh, eh, s);
        }
        *(short8*)(dp + (c0 >> 3) * 128) = v;
    }
    bbfNeg[cand] = -s;
}

// ---- kScr: MFMA screen + flags -> per-block queue (r16 kMF minus tail) -----
__global__ __launch_bounds__(256, 3) void kScr(const float* __restrict__ hs,
                                               const float* __restrict__ emb,
                                               float* __restrict__ out) {
    const float* A = out + SA_FLT;
    unsigned* qcount = (unsigned*)(out + SQC_FLT);
    const float* bbfNeg = out + SBB_FLT;
    unsigned* queue = (unsigned*)(out + SQ_FLT);
    const unsigned short* fbf = (const unsigned short*)(out + SFB_FLT);
    const unsigned short* ebf = (const unsigned short*)(out + SEB_FLT);

    __shared__ __align__(16) short As[32][264];   // A-tile, stride 132 dw
    __shared__ unsigned rowMaxOrd[32];
    __shared__ float margLds[32];
    __shared__ int lqn;

    const int t = threadIdx.x, blk = blockIdx.x;
    const int row0 = (blk >> 2) * 32;
    const int candSplit = (blk & 3) * 2048;
    const int lane = t & 63, wid = t >> 6;
    const int quad = lane >> 4, l15 = lane & 15;
    unsigned* qBlk = queue + (size_t)blk * QCAP;

    if (t < 32) {
        rowMaxOrd[t] = 0u;
        margLds[t] = 2.0e-5f * sqrtf(A[row0 + t]) + 4.0e-5f;
    }
    if (t == 0) lqn = 0;

    // stage A-tile ONCE: coalesced 16-B global loads, linear->2D LDS
    {
        const unsigned short* src = fbf + ((size_t)row0 << 8);
        #pragma unroll
        for (int i = 0; i < 4; ++i) {
            int idx = (i * 256 + t) * 8;          // linear short offset
            short8 v = *(const short8*)(src + idx);
            *(short8*)&As[idx >> 8][idx & 255] = v;
        }
    }
    __syncthreads();     // the ONLY barrier before the final qcount store

    // loop-invariant margins -> registers
    f32x4 mgv[2];
    #pragma unroll
    for (int m = 0; m < 2; ++m)
        mgv[m] = *(const f32x4*)&margLds[m * 16 + quad * 4];

    for (int cc = 0; cc < 8; ++cc) {
        const int candW = candSplit + cc * 256 + wid * 64;
        // per-wave panel base: lanes (quad,l15) -> contiguous 1KB per (jc,ks)
        const unsigned short* ebW = ebf + (((size_t)candW) << 8)
                                       + quad * 128 + l15 * 8;
        f32x4 acc[2][4];
        #pragma unroll
        for (int jc = 0; jc < 4; ++jc) {
            float bneg = bbfNeg[candW + jc * 16 + l15];
            #pragma unroll
            for (int m = 0; m < 2; ++m)
                acc[m][jc] = (f32x4){bneg, bneg, bneg, bneg};
        }
        #pragma unroll
        for (int ks = 0; ks < 8; ++ks) {
            short8 bf[4];
            #pragma unroll
            for (int jc = 0; jc < 4; ++jc)
                bf[jc] = *(const short8*)(ebW + jc * 4096 + ks * 512);
            #pragma unroll
            for (int m = 0; m < 2; ++m) {
                short8 af = *(const short8*)&As[m * 16 + l15][ks * 32 + quad * 8];
                #pragma unroll
                for (int jc = 0; jc < 4; ++jc)
                    acc[m][jc] = __builtin_amdgcn_mfma_f32_16x16x32_bf16(
                        af, bf[jc], acc[m][jc], 0, 0, 0);
            }
        }
        // flag: per-(m,reg) early-out; ballot consensus so the 16-lane
        // shuffle-max never runs with inactive lanes (garbage-max hazard).
        #pragma unroll
        for (int m = 0; m < 2; ++m) {
            uint32x4 thv = *(const uint32x4*)&rowMaxOrd[m * 16 + quad * 4];
            #pragma unroll
            for (int reg = 0; reg < 4; ++reg) {
                int rl = m * 16 + quad * 4 + reg;
                float vmax = fmaxf(fmaxf(acc[m][0][reg], acc[m][1][reg]),
                                   fmaxf(acc[m][2][reg], acc[m][3][reg]));
                unsigned th = thv[reg];
                float mg = mgv[m][reg];
                bool hot = ordU(__fadd_rn(vmax, mg)) >= th;
                unsigned long long bal = __ballot(hot);
                if (((bal >> (quad * 16)) & 0xFFFFull) == 0ull) continue;
                float g = vmax;                       // all 16 lanes active
                g = fmaxf(g, __shfl_xor(g, 1, 16));
                g = fmaxf(g, __shfl_xor(g, 2, 16));
                g = fmaxf(g, __shfl_xor(g, 4, 16));
                g = fmaxf(g, __shfl_xor(g, 8, 16));
                unsigned og = ordU(g);
                if (og > th) { atomicMax(&rowMaxOrd[rl], og); th = og; }
                #pragma unroll
                for (int jc = 0; jc < 4; ++jc) {
                    float x = acc[m][jc][reg];
                    if (ordU(__fadd_rn(x, mg)) >= th) {
                        int slot = atomicAdd(&lqn, 1);
                        if (slot < QCAP)
                            qBlk[slot] = ((unsigned)rl << 13)
                                       | (unsigned)(candW + jc * 16 + l15);
                    }
                }
            }
        }
    }
    __syncthreads();
    if (t == 0) qcount[blk] = (unsigned)lqn;
}

// ---- kTailE: F-staged exact re-rank of queued candidates (r16 tail) --------
__global__ __launch_bounds__(256, 4) void kTailE(const float* __restrict__ hs,
                                                 const float* __restrict__ emb,
                                                 float* __restrict__ out) {
    const float* A = out + SA_FLT;
    unsigned long long* keys = (unsigned long long*)(out + SK_FLT);
    const unsigned* qcount = (const unsigned*)(out + SQC_FLT);
    const unsigned* queue = (const unsigned*)(out + SQ_FLT);

    __shared__ __align__(16) float F[32][260];

    const int t = threadIdx.x, blk = blockIdx.x;
    const int row0 = (blk >> 2) * 32;
    const unsigned* qBlk = queue + (size_t)blk * QCAP;

    int n = (int)qcount[blk];             // uniform read -> uniform branch
    if (n == 0) return;
    if (n > QCAP) n = QCAP;               // overflow handled by kFallback

    // stage block's 32 rows fp32 VERBATIM into LDS (coalesced: for fixed c,
    // 32 consecutive rows are contiguous in hs)
    {
        int yl = t & 31, cq = t >> 5;     // cq 0..7
        int nrow = row0 + yl;
        int b = nrow >> 10, yx = nrow & 1023;
        const float* src = hs + ((size_t)b << 18) + yx;
        #pragma unroll
        for (int i = 0; i < 32; ++i) {
            int c = i * 8 + cq;
            F[yl][c] = src[(size_t)c << 10];
        }
    }
    __syncthreads();

    for (int i = t; i < n; i += 256) {
        unsigned e = qBlk[i];
        int rl = (int)(e >> 13), cand = (int)(e & 8191u);
        const float* ep = emb + ((size_t)cand << 8);
        float acc = 0.f;
        #pragma unroll 4
        for (int c0 = 0; c0 < 256; c0 += 4) {
            f32x4 f4 = *(const f32x4*)&F[rl][c0];     // LDS, exact hs copy
            f32x4 e4 = *(const f32x4*)(ep + c0);      // global fp32 emb
            acc = fmaf(f4[0], e4[0], acc);
            acc = fmaf(f4[1], e4[1], acc);
            acc = fmaf(f4[2], e4[2], acc);
            acc = fmaf(f4[3], e4[3], acc);
        }
        int row = row0 + rl;
        float d = __fsub_rn(A[row], __fadd_rn(acc, acc));
        unsigned long long key =
            ((unsigned long long)__float_as_uint(d) << 32) | (unsigned)cand;
        atomicMin(&keys[row], key);
    }
}

// ---- kFallback: exact full scan for overflowed blocks (normally no-op) -----
__global__ void kFallback(const float* __restrict__ hs, const float* __restrict__ emb,
                          float* __restrict__ out) {
    unsigned* qcount = (unsigned*)(out + SQC_FLT);
    if (qcount[blockIdx.x] <= QCAP) return;
    const float* A = out + SA_FLT;
    unsigned long long* keys = (unsigned long long*)(out + SK_FLT);
    int row0 = (int)(blockIdx.x >> 2) * 32, cb = (int)(blockIdx.x & 3) * 2048;
    for (int p = threadIdx.x; p < 32 * 2048; p += 256)
        exact_eval(hs, emb, A, keys, row0 + (p >> 11), cb + (p & 2047));
}

// ---- kPost / kLoss / kZQ (unchanged) ---------------------------------------
__global__ void kPost(float* __restrict__ out) {
    const unsigned long long* keys = (const unsigned long long*)(out + SK_FLT);
    double* lossAcc = (double*)(out + SL_FLT);
    __shared__ double sd[256];
    int n = blockIdx.x * 256 + threadIdx.x;
    unsigned long long key = keys[n];
    unsigned idx = (unsigned)(key & 0xffffffffu) & 8191u;
    float d = __uint_as_float((unsigned)(key >> 32));
    out[NELEM + n] = (float)idx;
    sd[threadIdx.x] = (double)d;
    __syncthreads();
    for (int s = 128; s > 0; s >>= 1) {
        if (threadIdx.x < s) sd[threadIdx.x] += sd[threadIdx.x + s];
        __syncthreads();
    }
    if (threadIdx.x == 0) atomicAdd(lossAcc, sd[0]);
}

__global__ void kLoss(float* __restrict__ out) {
    if (threadIdx.x == 0) {
        double loss = 1.25 * (*(const double*)(out + SL_FLT)) / (double)NELEM;
        out[NELEM + N_ROWS] = (float)loss;
    }
}

__global__ void kZQ(const float* __restrict__ hs, const float* __restrict__ emb,
                    float* __restrict__ out) {
    int o = blockIdx.x * 256 + threadIdx.x;
    int n = (o & 1023) | ((o >> 18) << 10);
    int c = (o >> 10) & 255;
    unsigned idx = (unsigned)out[NELEM + n] & 8191u;
    float e = emb[((size_t)idx << 8) + c];
    float h = hs[o];
    out[o] = __fadd_rn(h, __fsub_rn(e, h));
}

extern "C" void kernel_launch(void* const* d_in, const int* in_sizes, int n_in,
                              void* d_out, int out_size, void* d_ws, size_t ws_size,
                              hipStream_t stream) {
    const float* hs  = (const float*)d_in[0];
    const float* emb = (const float*)d_in[1];
    float* out = (float*)d_out;

    kA<<<N_ROWS / 256, 256, 0, stream>>>(hs, out);
    kFbf<<<1024, 256, 0, stream>>>(hs, out);
    kEbf<<<K_CAND / 256, 256, 0, stream>>>(emb, out);
    kScr<<<2048, 256, 0, stream>>>(hs, emb, out);
    kTailE<<<2048, 256, 0, stream>>>(hs, emb, out);
    kFallback<<<2048, 256, 0, stream>>>(hs, emb, out);
    kPost<<<N_ROWS / 256, 256, 0, stream>>>(out);
    kLoss<<<1, 64, 0, stream>>>(out);
    kZQ<<<NELEM / 256, 256, 0, stream>>>(hs, emb, out);
}

// Round 8
// 355.398 us; speedup vs baseline: 1.1498x; 1.0678x over previous
//
#include <hip/hip_runtime.h>

// VectorQuantizer: N=16384 rows, C=256, K=8192. inputs fp32, outputs fp32
// (z_q 4194304 ++ indices 16384 ++ loss 1).
// r17 ablation: kScr(screen)=148us MfmaUtil 19.6 VALUBusy 33.4 VGPR 84
// (reg-cap fingerprint GONE at launch_bounds(256,3)); WRITE mystery lives
// in the tail, not screen. Screen is VALU-amortization-bound: per cc
// 64 MFMA (~310cyc) vs ~250 VALU ops (B-addr + ds-addr + 8 flag blocks).
// r18: kScr -> 64-row blocks acc[4][4] (r13's PASSING body, minus hoist,
// minus tail) at (256,3): 64 AGPR + ~100 VGPR fits under the 170 cap that
// killed r12/r14's version of this shape. 2x MFMA per cc at constant
// B-load/addressing. Dual half-queues (h = m>=2, wave-uniform) keep kTailE
// byte-identical at its proven 32-row/2048-block shape; kFallback folded
// into kTailE overflow branch; tail unroll 8; kA/kEbf grids widened 4x.
//
// margin_n = 2e-5*sqrt(A_n) + 4e-5; flag iff R~ + margin >= rowRunningMax
// (monotone LDS atomicMax, per 64-row x candSplit block; stale threshold
// only over-flags => safe). Exact path: F verbatim hs copy in LDS,
// sequential fmaf chain, u64 key tie-break -- byte-identical to r9-r17.
//
// Scratch in z_q float region of d_out (kZQ overwrites last); no d_ws.
// High-water 4,483,080 floats (= r14/r16/r17's proven-safe envelope).

#define N_ROWS 16384
#define K_CAND 8192
#define CDIM   256
#define NELEM  4194304

#define SA_FLT   0          // A[16384] fp32 (numpy-pairwise-exact)
#define SK_FLT   16384      // keys u64[16384]
#define SL_FLT   49152      // lossAcc double
#define SQC_FLT  49160      // qcount u32[2048]
#define SBB_FLT  51208      // -B~ f32[8192]
#define SQ_FLT   59400      // queue u32[2048*624]
#define SFB_FLT  1337352    // fbf = bf16(2*f)[16384][256] as u16
#define SEB_FLT  3434504    // ebf2 = bf16(e) 16-cand panels (ends 4483080)
#define QCAP     624

typedef __attribute__((ext_vector_type(8))) short short8;
typedef __attribute__((ext_vector_type(4))) float f32x4;
typedef __attribute__((ext_vector_type(4))) unsigned uint32x4;

__device__ __forceinline__ unsigned short f2bf_rne(float x) {
    unsigned u = __float_as_uint(x);
    return (unsigned short)((u + 0x7fffu + ((u >> 16) & 1u)) >> 16);
}
__device__ __forceinline__ float bf2f(unsigned short u) {
    return __uint_as_float(((unsigned)u) << 16);
}
// monotone float->u32 map (handles negatives)
__device__ __forceinline__ unsigned ordU(float f) {
    unsigned u = __float_as_uint(f);
    return u ^ (((int)u >> 31) | 0x80000000u);
}

// ---- kA: numpy-pairwise-exact A[n]; init keys + loss -----------------------
// r18: 64-thread blocks, grid 256 (was 64 blocks -> <1/4 of CUs active)
__global__ void kA(const float* __restrict__ hs, float* __restrict__ out) {
    float* A = out + SA_FLT;
    unsigned long long* keys = (unsigned long long*)(out + SK_FLT);
    int n = blockIdx.x * 64 + threadIdx.x;
    keys[n] = ~0ull;
    if (n == 0) *(double*)(out + SL_FLT) = 0.0;
    int b = n >> 10, yx = n & 1023;
    const float* base = hs + ((size_t)b << 18) + yx;
    float hsum[2];
    for (int h = 0; h < 2; ++h) {
        float r[8];
        #pragma unroll
        for (int j = 0; j < 8; ++j) {
            float x = base[(size_t)(h * 128 + j) << 10];
            r[j] = __fmul_rn(x, x);
        }
        for (int i = 8; i < 128; i += 8) {
            #pragma unroll
            for (int j = 0; j < 8; ++j) {
                float x = base[(size_t)(h * 128 + i + j) << 10];
                r[j] = __fadd_rn(r[j], __fmul_rn(x, x));
            }
        }
        hsum[h] = __fadd_rn(
            __fadd_rn(__fadd_rn(r[0], r[1]), __fadd_rn(r[2], r[3])),
            __fadd_rn(__fadd_rn(r[4], r[5]), __fadd_rn(r[6], r[7])));
    }
    A[n] = __fadd_rn(hsum[0], hsum[1]);
}

// ---- kFbf: (b,c,yx) -> bf16(2*f)[n][c] via LDS transpose -------------------
__global__ void kFbf(const float* __restrict__ hs, float* __restrict__ out) {
    unsigned short* fbf = (unsigned short*)(out + SFB_FLT);
    __shared__ float T[64][65];
    int blk = blockIdx.x;                 // 16 b x 4 cBlk x 16 yBlk = 1024
    int b = blk >> 6, cB = (blk >> 4) & 3, yB = blk & 15;
    int t = threadIdx.x;
    int yl = t & 63, ch = t >> 6;
    const float* src = hs + ((size_t)b << 18) + (((size_t)cB * 64) << 10) + yB * 64 + yl;
    #pragma unroll
    for (int i = 0; i < 16; ++i) {
        int c = ch * 16 + i;
        T[c][yl] = src[(size_t)c << 10];
    }
    __syncthreads();
    int yr = t >> 2, cs = (t & 3) * 16;
    short8 v0, v1;
    #pragma unroll
    for (int j = 0; j < 8; ++j) {
        v0[j] = (short)f2bf_rne(2.0f * T[cs + j][yr]);
        v1[j] = (short)f2bf_rne(2.0f * T[cs + 8 + j][yr]);
    }
    unsigned short* dst = fbf + (((size_t)(b * 1024 + yB * 64 + yr)) << 8) + cB * 64 + cs;
    *(short8*)dst = v0;
    *(short8*)(dst + 8) = v1;
}

// ---- kEbf: bf16(e) -> 16-cand panel layout + (-B~) -------------------------
// ebf2 layout (shorts): g=cand>>4, kc=c0/8 (0..31), cl=cand&15:
//   addr = g*4096 + kc*128 + cl*8   (panel 8KB, chunk row 256B, 16B/cand)
// r18: 64-thread blocks, grid 128 (was 32 blocks)
__global__ void kEbf(const float* __restrict__ emb, float* __restrict__ out) {
    unsigned short* ebf = (unsigned short*)(out + SEB_FLT);
    float* bbfNeg = out + SBB_FLT;
    int cand = blockIdx.x * 64 + threadIdx.x;
    const float* ep = emb + ((size_t)cand << 8);
    unsigned short* dp = ebf + (((size_t)(cand >> 4)) << 12) + (cand & 15) * 8;
    float s = 0.f;
    for (int c0 = 0; c0 < 256; c0 += 8) {
        short8 v;
        #pragma unroll
        for (int j = 0; j < 8; ++j) {
            unsigned short bb = f2bf_rne(ep[c0 + j]);
            v[j] = (short)bb;
            float eh = bf2f(bb);
            s = fmaf(eh, eh, s);
        }
        *(short8*)(dp + (c0 >> 3) * 128) = v;
    }
    bbfNeg[cand] = -s;
}

// ---- kScr: MFMA screen + flags -> per-half queues (r13 body, 64 rows) ------
// grid 1024 = 256 rowBlk x 4 candSplit. acc[4][4] = 64 AGPR; cap 170.
__global__ __launch_bounds__(256, 3) void kScr(const float* __restrict__ hs,
                                               const float* __restrict__ emb,
                                               float* __restrict__ out) {
    const float* A = out + SA_FLT;
    unsigned* qcount = (unsigned*)(out + SQC_FLT);
    const float* bbfNeg = out + SBB_FLT;
    unsigned* queue = (unsigned*)(out + SQ_FLT);
    const unsigned short* fbf = (const unsigned short*)(out + SFB_FLT);
    const unsigned short* ebf = (const unsigned short*)(out + SEB_FLT);

    __shared__ __align__(16) short As[64][264];   // A-tile, stride 132 dw
    __shared__ unsigned rowMaxOrd[64];
    __shared__ float margLds[64];
    __shared__ int lqnH[2];

    const int t = threadIdx.x, blk = blockIdx.x;
    const int row0 = (blk >> 2) * 64;
    const int candSplit = (blk & 3) * 2048;
    const int lane = t & 63, wid = t >> 6;
    const int quad = lane >> 4, l15 = lane & 15;
    // tail-block queue indices for the two 32-row halves:
    // qb = rowBlk32*4 + split, rowBlk32 = (blk>>2)*2 + h
    const int qb0 = (blk >> 2) * 8 + (blk & 3);
    unsigned* qB[2] = { queue + (size_t)qb0 * QCAP,
                        queue + (size_t)(qb0 + 4) * QCAP };

    if (t < 64) {
        rowMaxOrd[t] = 0u;
        margLds[t] = 2.0e-5f * sqrtf(A[row0 + t]) + 4.0e-5f;
    }
    if (t < 2) lqnH[t] = 0;

    // stage A-tile ONCE: coalesced 16-B global loads, linear->2D LDS
    {
        const unsigned short* src = fbf + ((size_t)row0 << 8);
        #pragma unroll
        for (int i = 0; i < 8; ++i) {
            int idx = (i * 256 + t) * 8;          // linear short offset
            short8 v = *(const short8*)(src + idx);
            *(short8*)&As[idx >> 8][idx & 255] = v;
        }
    }
    __syncthreads();     // the ONLY barrier before the final qcount store

    // loop-invariant margins -> registers (one batched LDS read per m)
    f32x4 mgv[4];
    #pragma unroll
    for (int m = 0; m < 4; ++m)
        mgv[m] = *(const f32x4*)&margLds[m * 16 + quad * 4];

    for (int cc = 0; cc < 8; ++cc) {
        const int candW = candSplit + cc * 256 + wid * 64;
        // per-wave panel base: lanes (quad,l15) -> contiguous 1KB per (jc,ks)
        const unsigned short* ebW = ebf + (((size_t)candW) << 8)
                                       + quad * 128 + l15 * 8;
        f32x4 acc[4][4];
        #pragma unroll
        for (int jc = 0; jc < 4; ++jc) {
            float bneg = bbfNeg[candW + jc * 16 + l15];
            #pragma unroll
            for (int m = 0; m < 4; ++m)
                acc[m][jc] = (f32x4){bneg, bneg, bneg, bneg};
        }
        #pragma unroll
        for (int ks = 0; ks < 8; ++ks) {
            short8 bf[4];
            #pragma unroll
            for (int jc = 0; jc < 4; ++jc)
                bf[jc] = *(const short8*)(ebW + jc * 4096 + ks * 512);
            #pragma unroll
            for (int m = 0; m < 4; ++m) {
                short8 af = *(const short8*)&As[m * 16 + l15][ks * 32 + quad * 8];
                #pragma unroll
                for (int jc = 0; jc < 4; ++jc)
                    acc[m][jc] = __builtin_amdgcn_mfma_f32_16x16x32_bf16(
                        af, bf[jc], acc[m][jc], 0, 0, 0);
            }
        }
        // flag: per-(m,reg) early-out; ballot consensus so the 16-lane
        // shuffle-max never runs with inactive lanes (garbage-max hazard).
        #pragma unroll
        for (int m = 0; m < 4; ++m) {
            uint32x4 thv = *(const uint32x4*)&rowMaxOrd[m * 16 + quad * 4];
            #pragma unroll
            for (int reg = 0; reg < 4; ++reg) {
                int rl = m * 16 + quad * 4 + reg;
                float vmax = fmaxf(fmaxf(acc[m][0][reg], acc[m][1][reg]),
                                   fmaxf(acc[m][2][reg], acc[m][3][reg]));
                unsigned th = thv[reg];
                float mg = mgv[m][reg];
                bool hot = ordU(__fadd_rn(vmax, mg)) >= th;
                unsigned long long bal = __ballot(hot);
                if (((bal >> (quad * 16)) & 0xFFFFull) == 0ull) continue;
                float g = vmax;                       // all 16 lanes active
                g = fmaxf(g, __shfl_xor(g, 1, 16));
                g = fmaxf(g, __shfl_xor(g, 2, 16));
                g = fmaxf(g, __shfl_xor(g, 4, 16));
                g = fmaxf(g, __shfl_xor(g, 8, 16));
                unsigned og = ordU(g);
                if (og > th) { atomicMax(&rowMaxOrd[rl], og); th = og; }
                #pragma unroll
                for (int jc = 0; jc < 4; ++jc) {
                    float x = acc[m][jc][reg];
                    if (ordU(__fadd_rn(x, mg)) >= th) {
                        int slot = atomicAdd(&lqnH[m >> 1], 1);
                        if (slot < QCAP)
                            qB[m >> 1][slot] = ((unsigned)(rl & 31) << 13)
                                             | (unsigned)(candW + jc * 16 + l15);
                    }
                }
            }
        }
    }
    __syncthreads();
    if (t < 2) qcount[qb0 + t * 4] = (unsigned)lqnH[t];
}

// ---- kTailE: F-staged exact re-rank of queued candidates (+fallback) -------
// grid 2048, 32 rows/block. Exact chain byte-identical to r9-r17.
__global__ __launch_bounds__(256, 4) void kTailE(const float* __restrict__ hs,
                                                 const float* __restrict__ emb,
                                                 float* __restrict__ out) {
    const float* A = out + SA_FLT;
    unsigned long long* keys = (unsigned long long*)(out + SK_FLT);
    const unsigned* qcount = (const unsigned*)(out + SQC_FLT);
    const unsigned* queue = (const unsigned*)(out + SQ_FLT);

    __shared__ __align__(16) float F[32][260];

    const int t = threadIdx.x, blk = blockIdx.x;
    const int row0 = (blk >> 2) * 32;
    const unsigned* qBlk = queue + (size_t)blk * QCAP;

    int n = (int)qcount[blk];             // uniform read -> uniform branch
    if (n == 0) return;

    // stage block's 32 rows fp32 VERBATIM into LDS (coalesced: for fixed c,
    // 32 consecutive rows are contiguous in hs)
    {
        int yl = t & 31, cq = t >> 5;     // cq 0..7
        int nrow = row0 + yl;
        int b = nrow >> 10, yx = nrow & 1023;
        const float* src = hs + ((size_t)b << 18) + yx;
        #pragma unroll
        for (int i = 0; i < 32; ++i) {
            int c = i * 8 + cq;
            F[yl][c] = src[(size_t)c << 10];
        }
    }
    __syncthreads();

    if (n > QCAP) {                       // overflow: exact full scan (rare)
        int cb = (blk & 3) * 2048;
        for (int p = t; p < 32 * 2048; p += 256) {
            int rl = p >> 11, cand = cb + (p & 2047);
            const float* ep = emb + ((size_t)cand << 8);
            float acc = 0.f;
            #pragma unroll 8
            for (int c0 = 0; c0 < 256; c0 += 4) {
                f32x4 f4 = *(const f32x4*)&F[rl][c0];
                f32x4 e4 = *(const f32x4*)(ep + c0);
                acc = fmaf(f4[0], e4[0], acc);
                acc = fmaf(f4[1], e4[1], acc);
                acc = fmaf(f4[2], e4[2], acc);
                acc = fmaf(f4[3], e4[3], acc);
            }
            int row = row0 + rl;
            float d = __fsub_rn(A[row], __fadd_rn(acc, acc));
            unsigned long long key =
                ((unsigned long long)__float_as_uint(d) << 32) | (unsigned)cand;
            atomicMin(&keys[row], key);
        }
        return;
    }

    for (int i = t; i < n; i += 256) {
        unsigned e = qBlk[i];
        int rl = (int)(e >> 13), cand = (int)(e & 8191u);
        const float* ep = emb + ((size_t)cand << 8);
        float acc = 0.f;
        #pragma unroll 8
        for (int c0 = 0; c0 < 256; c0 += 4) {
            f32x4 f4 = *(const f32x4*)&F[rl][c0];     // LDS, exact hs copy
            f32x4 e4 = *(const f32x4*)(ep + c0);      // global fp32 emb
            acc = fmaf(f4[0], e4[0], acc);
            acc = fmaf(f4[1], e4[1], acc);
            acc = fmaf(f4[2], e4[2], acc);
            acc = fmaf(f4[3], e4[3], acc);
        }
        int row = row0 + rl;
        float d = __fsub_rn(A[row], __fadd_rn(acc, acc));
        unsigned long long key =
            ((unsigned long long)__float_as_uint(d) << 32) | (unsigned)cand;
        atomicMin(&keys[row], key);
    }
}

// ---- kPost / kLoss / kZQ (unchanged) ---------------------------------------
__global__ void kPost(float* __restrict__ out) {
    const unsigned long long* keys = (const unsigned long long*)(out + SK_FLT);
    double* lossAcc = (double*)(out + SL_FLT);
    __shared__ double sd[256];
    int n = blockIdx.x * 256 + threadIdx.x;
    unsigned long long key = keys[n];
    unsigned idx = (unsigned)(key & 0xffffffffu) & 8191u;
    float d = __uint_as_float((unsigned)(key >> 32));
    out[NELEM + n] = (float)idx;
    sd[threadIdx.x] = (double)d;
    __syncthreads();
    for (int s = 128; s > 0; s >>= 1) {
        if (threadIdx.x < s) sd[threadIdx.x] += sd[threadIdx.x + s];
        __syncthreads();
    }
    if (threadIdx.x == 0) atomicAdd(lossAcc, sd[0]);
}

__global__ void kLoss(float* __restrict__ out) {
    if (threadIdx.x == 0) {
        double loss = 1.25 * (*(const double*)(out + SL_FLT)) / (double)NELEM;
        out[NELEM + N_ROWS] = (float)loss;
    }
}

__global__ void kZQ(const float* __restrict__ hs, const float* __restrict__ emb,
                    float* __restrict__ out) {
    int o = blockIdx.x * 256 + threadIdx.x;
    int n = (o & 1023) | ((o >> 18) << 10);
    int c = (o >> 10) & 255;
    unsigned idx = (unsigned)out[NELEM + n] & 8191u;
    float e = emb[((size_t)idx << 8) + c];
    float h = hs[o];
    out[o] = __fadd_rn(h, __fsub_rn(e, h));
}

extern "C" void kernel_launch(void* const* d_in, const int* in_sizes, int n_in,
                              void* d_out, int out_size, void* d_ws, size_t ws_size,
                              hipStream_t stream) {
    const float* hs  = (const float*)d_in[0];
    const float* emb = (const float*)d_in[1];
    float* out = (float*)d_out;

    kA<<<N_ROWS / 64, 64, 0, stream>>>(hs, out);
    kFbf<<<1024, 256, 0, stream>>>(hs, out);
    kEbf<<<K_CAND / 64, 64, 0, stream>>>(emb, out);
    kScr<<<1024, 256, 0, stream>>>(hs, emb, out);
    kTailE<<<2048, 256, 0, stream>>>(hs, emb, out);
    kPost<<<N_ROWS / 256, 256, 0, stream>>>(out);
    kLoss<<<1, 64, 0, stream>>>(out);
    kZQ<<<NELEM / 256, 256, 0, stream>>>(hs, emb, out);
}

// Round 9
// 349.865 us; speedup vs baseline: 1.1679x; 1.0158x over previous
//
#include <hip/hip_runtime.h>

// VectorQuantizer: N=16384 rows, C=256, K=8192. inputs fp32, outputs fp32
// (z_q 4194304 ++ indices 16384 ++ loss 1).
// r18: kScr(64-row, acc[4][4], (256,3)) 138us; VALUBusy pinned at 33.4 ->
// flag VALU scales with OUTPUT TILES not blocks (amortization only hit the
// B-load side, -7%). Pipes sum 54% -> 46% stall at reg-capped 3 waves/SIMD
// (148 regs). Chain audit: each cc STARTS with 4 bbfNeg L2 loads gating 64
// acc inits gating all MFMAs (~250cyc serial lead-in x8 cc, unhidable).
// r19: (1) kScr: acc init 0; bneg folded into flag phase as fp32 add (loads
//      issue at cc start, latency hides under MFMA block). R~ changes by one
//      fp32-add reordering (~1e-7 << margin 3.6e-4); criterion/queue/exact
//      path byte-identical.
//      (2) kZQ: 64n x 64c LDS-tiled emb gather (256B/row coalesced vs 256
//      scattered 4B lines per block = 16x fewer transactions). Formula
//      __fadd_rn(h,__fsub_rn(e,h)) byte-identical.
//      (3) kA/kEbf reverted to r17 grids (r18 regrid bought nothing; 30ms
//      kA profile entry was a replay artifact -- insurance).
//
// margin_n = 2e-5*sqrt(A_n) + 4e-5; flag iff R~ + margin >= rowRunningMax
// (monotone LDS atomicMax, per 64-row x candSplit block; stale threshold
// only over-flags => safe). Exact path: F verbatim hs copy in LDS,
// sequential fmaf chain, u64 key tie-break -- byte-identical to r9-r18.
//
// Scratch in z_q float region of d_out (kZQ overwrites last); no d_ws.
// High-water 4,483,080 floats (= r14-r18's proven-safe envelope).

#define N_ROWS 16384
#define K_CAND 8192
#define CDIM   256
#define NELEM  4194304

#define SA_FLT   0          // A[16384] fp32 (numpy-pairwise-exact)
#define SK_FLT   16384      // keys u64[16384]
#define SL_FLT   49152      // lossAcc double
#define SQC_FLT  49160      // qcount u32[2048]
#define SBB_FLT  51208      // -B~ f32[8192]
#define SQ_FLT   59400      // queue u32[2048*624]
#define SFB_FLT  1337352    // fbf = bf16(2*f)[16384][256] as u16
#define SEB_FLT  3434504    // ebf2 = bf16(e) 16-cand panels (ends 4483080)
#define QCAP     624

typedef __attribute__((ext_vector_type(8))) short short8;
typedef __attribute__((ext_vector_type(4))) float f32x4;
typedef __attribute__((ext_vector_type(4))) unsigned uint32x4;

__device__ __forceinline__ unsigned short f2bf_rne(float x) {
    unsigned u = __float_as_uint(x);
    return (unsigned short)((u + 0x7fffu + ((u >> 16) & 1u)) >> 16);
}
__device__ __forceinline__ float bf2f(unsigned short u) {
    return __uint_as_float(((unsigned)u) << 16);
}
// monotone float->u32 map (handles negatives)
__device__ __forceinline__ unsigned ordU(float f) {
    unsigned u = __float_as_uint(f);
    return u ^ (((int)u >> 31) | 0x80000000u);
}

// ---- kA: numpy-pairwise-exact A[n]; init keys + loss -----------------------
__global__ void kA(const float* __restrict__ hs, float* __restrict__ out) {
    float* A = out + SA_FLT;
    unsigned long long* keys = (unsigned long long*)(out + SK_FLT);
    int n = blockIdx.x * 256 + threadIdx.x;
    keys[n] = ~0ull;
    if (n == 0) *(double*)(out + SL_FLT) = 0.0;
    int b = n >> 10, yx = n & 1023;
    const float* base = hs + ((size_t)b << 18) + yx;
    float hsum[2];
    for (int h = 0; h < 2; ++h) {
        float r[8];
        #pragma unroll
        for (int j = 0; j < 8; ++j) {
            float x = base[(size_t)(h * 128 + j) << 10];
            r[j] = __fmul_rn(x, x);
        }
        for (int i = 8; i < 128; i += 8) {
            #pragma unroll
            for (int j = 0; j < 8; ++j) {
                float x = base[(size_t)(h * 128 + i + j) << 10];
                r[j] = __fadd_rn(r[j], __fmul_rn(x, x));
            }
        }
        hsum[h] = __fadd_rn(
            __fadd_rn(__fadd_rn(r[0], r[1]), __fadd_rn(r[2], r[3])),
            __fadd_rn(__fadd_rn(r[4], r[5]), __fadd_rn(r[6], r[7])));
    }
    A[n] = __fadd_rn(hsum[0], hsum[1]);
}

// ---- kFbf: (b,c,yx) -> bf16(2*f)[n][c] via LDS transpose -------------------
__global__ void kFbf(const float* __restrict__ hs, float* __restrict__ out) {
    unsigned short* fbf = (unsigned short*)(out + SFB_FLT);
    __shared__ float T[64][65];
    int blk = blockIdx.x;                 // 16 b x 4 cBlk x 16 yBlk = 1024
    int b = blk >> 6, cB = (blk >> 4) & 3, yB = blk & 15;
    int t = threadIdx.x;
    int yl = t & 63, ch = t >> 6;
    const float* src = hs + ((size_t)b << 18) + (((size_t)cB * 64) << 10) + yB * 64 + yl;
    #pragma unroll
    for (int i = 0; i < 16; ++i) {
        int c = ch * 16 + i;
        T[c][yl] = src[(size_t)c << 10];
    }
    __syncthreads();
    int yr = t >> 2, cs = (t & 3) * 16;
    short8 v0, v1;
    #pragma unroll
    for (int j = 0; j < 8; ++j) {
        v0[j] = (short)f2bf_rne(2.0f * T[cs + j][yr]);
        v1[j] = (short)f2bf_rne(2.0f * T[cs + 8 + j][yr]);
    }
    unsigned short* dst = fbf + (((size_t)(b * 1024 + yB * 64 + yr)) << 8) + cB * 64 + cs;
    *(short8*)dst = v0;
    *(short8*)(dst + 8) = v1;
}

// ---- kEbf: bf16(e) -> 16-cand panel layout + (-B~) -------------------------
// ebf2 layout (shorts): g=cand>>4, kc=c0/8 (0..31), cl=cand&15:
//   addr = g*4096 + kc*128 + cl*8   (panel 8KB, chunk row 256B, 16B/cand)
__global__ void kEbf(const float* __restrict__ emb, float* __restrict__ out) {
    unsigned short* ebf = (unsigned short*)(out + SEB_FLT);
    float* bbfNeg = out + SBB_FLT;
    int cand = blockIdx.x * 256 + threadIdx.x;   // grid 32
    const float* ep = emb + ((size_t)cand << 8);
    unsigned short* dp = ebf + (((size_t)(cand >> 4)) << 12) + (cand & 15) * 8;
    float s = 0.f;
    for (int c0 = 0; c0 < 256; c0 += 8) {
        short8 v;
        #pragma unroll
        for (int j = 0; j < 8; ++j) {
            unsigned short bb = f2bf_rne(ep[c0 + j]);
            v[j] = (short)bb;
            float eh = bf2f(bb);
            s = fmaf(eh, eh, s);
        }
        *(short8*)(dp + (c0 >> 3) * 128) = v;
    }
    bbfNeg[cand] = -s;
}

// ---- kScr: MFMA screen + flags -> per-half queues --------------------------
// grid 1024 = 256 rowBlk x 4 candSplit. acc[4][4] = 64 AGPR; cap 170.
// r19: acc init 0 (no load dependency); bneg folded into flag phase.
__global__ __launch_bounds__(256, 3) void kScr(const float* __restrict__ hs,
                                               const float* __restrict__ emb,
                                               float* __restrict__ out) {
    const float* A = out + SA_FLT;
    unsigned* qcount = (unsigned*)(out + SQC_FLT);
    const float* bbfNeg = out + SBB_FLT;
    unsigned* queue = (unsigned*)(out + SQ_FLT);
    const unsigned short* fbf = (const unsigned short*)(out + SFB_FLT);
    const unsigned short* ebf = (const unsigned short*)(out + SEB_FLT);

    __shared__ __align__(16) short As[64][264];   // A-tile, stride 132 dw
    __shared__ unsigned rowMaxOrd[64];
    __shared__ float margLds[64];
    __shared__ int lqnH[2];

    const int t = threadIdx.x, blk = blockIdx.x;
    const int row0 = (blk >> 2) * 64;
    const int candSplit = (blk & 3) * 2048;
    const int lane = t & 63, wid = t >> 6;
    const int quad = lane >> 4, l15 = lane & 15;
    // tail-block queue indices for the two 32-row halves:
    // qb = rowBlk32*4 + split, rowBlk32 = (blk>>2)*2 + h
    const int qb0 = (blk >> 2) * 8 + (blk & 3);
    unsigned* qB[2] = { queue + (size_t)qb0 * QCAP,
                        queue + (size_t)(qb0 + 4) * QCAP };

    if (t < 64) {
        rowMaxOrd[t] = 0u;
        margLds[t] = 2.0e-5f * sqrtf(A[row0 + t]) + 4.0e-5f;
    }
    if (t < 2) lqnH[t] = 0;

    // stage A-tile ONCE: coalesced 16-B global loads, linear->2D LDS
    {
        const unsigned short* src = fbf + ((size_t)row0 << 8);
        #pragma unroll
        for (int i = 0; i < 8; ++i) {
            int idx = (i * 256 + t) * 8;          // linear short offset
            short8 v = *(const short8*)(src + idx);
            *(short8*)&As[idx >> 8][idx & 255] = v;
        }
    }
    __syncthreads();     // the ONLY barrier before the final qcount store

    // loop-invariant margins -> registers (one batched LDS read per m)
    f32x4 mgv[4];
    #pragma unroll
    for (int m = 0; m < 4; ++m)
        mgv[m] = *(const f32x4*)&margLds[m * 16 + quad * 4];

    for (int cc = 0; cc < 8; ++cc) {
        const int candW = candSplit + cc * 256 + wid * 64;
        // per-wave panel base: lanes (quad,l15) -> contiguous 1KB per (jc,ks)
        const unsigned short* ebW = ebf + (((size_t)candW) << 8)
                                       + quad * 128 + l15 * 8;
        // bneg loads issue HERE, first used in flag phase -> latency hides
        // under the whole MFMA block (was: serial lead-in gating acc init)
        float bneg[4];
        #pragma unroll
        for (int jc = 0; jc < 4; ++jc)
            bneg[jc] = bbfNeg[candW + jc * 16 + l15];

        f32x4 acc[4][4];
        #pragma unroll
        for (int jc = 0; jc < 4; ++jc)
            #pragma unroll
            for (int m = 0; m < 4; ++m)
                acc[m][jc] = (f32x4){0.f, 0.f, 0.f, 0.f};
        #pragma unroll
        for (int ks = 0; ks < 8; ++ks) {
            short8 bf[4];
            #pragma unroll
            for (int jc = 0; jc < 4; ++jc)
                bf[jc] = *(const short8*)(ebW + jc * 4096 + ks * 512);
            #pragma unroll
            for (int m = 0; m < 4; ++m) {
                short8 af = *(const short8*)&As[m * 16 + l15][ks * 32 + quad * 8];
                #pragma unroll
                for (int jc = 0; jc < 4; ++jc)
                    acc[m][jc] = __builtin_amdgcn_mfma_f32_16x16x32_bf16(
                        af, bf[jc], acc[m][jc], 0, 0, 0);
            }
        }
        // flag: per-(m,reg) early-out; ballot consensus so the 16-lane
        // shuffle-max never runs with inactive lanes (garbage-max hazard).
        // x = acc + bneg (one fp32 add; was accumulated from bneg init).
        #pragma unroll
        for (int m = 0; m < 4; ++m) {
            uint32x4 thv = *(const uint32x4*)&rowMaxOrd[m * 16 + quad * 4];
            #pragma unroll
            for (int reg = 0; reg < 4; ++reg) {
                int rl = m * 16 + quad * 4 + reg;
                float x0 = __fadd_rn(acc[m][0][reg], bneg[0]);
                float x1 = __fadd_rn(acc[m][1][reg], bneg[1]);
                float x2 = __fadd_rn(acc[m][2][reg], bneg[2]);
                float x3 = __fadd_rn(acc[m][3][reg], bneg[3]);
                float vmax = fmaxf(fmaxf(x0, x1), fmaxf(x2, x3));
                unsigned th = thv[reg];
                float mg = mgv[m][reg];
                bool hot = ordU(__fadd_rn(vmax, mg)) >= th;
                unsigned long long bal = __ballot(hot);
                if (((bal >> (quad * 16)) & 0xFFFFull) == 0ull) continue;
                float g = vmax;                       // all 16 lanes active
                g = fmaxf(g, __shfl_xor(g, 1, 16));
                g = fmaxf(g, __shfl_xor(g, 2, 16));
                g = fmaxf(g, __shfl_xor(g, 4, 16));
                g = fmaxf(g, __shfl_xor(g, 8, 16));
                unsigned og = ordU(g);
                if (og > th) { atomicMax(&rowMaxOrd[rl], og); th = og; }
                float xs[4] = {x0, x1, x2, x3};
                #pragma unroll
                for (int jc = 0; jc < 4; ++jc) {
                    if (ordU(__fadd_rn(xs[jc], mg)) >= th) {
                        int slot = atomicAdd(&lqnH[m >> 1], 1);
                        if (slot < QCAP)
                            qB[m >> 1][slot] = ((unsigned)(rl & 31) << 13)
                                             | (unsigned)(candW + jc * 16 + l15);
                    }
                }
            }
        }
    }
    __syncthreads();
    if (t < 2) qcount[qb0 + t * 4] = (unsigned)lqnH[t];
}

// ---- kTailE: F-staged exact re-rank of queued candidates (+fallback) -------
// grid 2048, 32 rows/block. Exact chain byte-identical to r9-r18.
__global__ __launch_bounds__(256, 4) void kTailE(const float* __restrict__ hs,
                                                 const float* __restrict__ emb,
                                                 float* __restrict__ out) {
    const float* A = out + SA_FLT;
    unsigned long long* keys = (unsigned long long*)(out + SK_FLT);
    const unsigned* qcount = (const unsigned*)(out + SQC_FLT);
    const unsigned* queue = (const unsigned*)(out + SQ_FLT);

    __shared__ __align__(16) float F[32][260];

    const int t = threadIdx.x, blk = blockIdx.x;
    const int row0 = (blk >> 2) * 32;
    const unsigned* qBlk = queue + (size_t)blk * QCAP;

    int n = (int)qcount[blk];             // uniform read -> uniform branch
    if (n == 0) return;

    // stage block's 32 rows fp32 VERBATIM into LDS (coalesced: for fixed c,
    // 32 consecutive rows are contiguous in hs)
    {
        int yl = t & 31, cq = t >> 5;     // cq 0..7
        int nrow = row0 + yl;
        int b = nrow >> 10, yx = nrow & 1023;
        const float* src = hs + ((size_t)b << 18) + yx;
        #pragma unroll
        for (int i = 0; i < 32; ++i) {
            int c = i * 8 + cq;
            F[yl][c] = src[(size_t)c << 10];
        }
    }
    __syncthreads();

    if (n > QCAP) {                       // overflow: exact full scan (rare)
        int cb = (blk & 3) * 2048;
        for (int p = t; p < 32 * 2048; p += 256) {
            int rl = p >> 11, cand = cb + (p & 2047);
            const float* ep = emb + ((size_t)cand << 8);
            float acc = 0.f;
            #pragma unroll 8
            for (int c0 = 0; c0 < 256; c0 += 4) {
                f32x4 f4 = *(const f32x4*)&F[rl][c0];
                f32x4 e4 = *(const f32x4*)(ep + c0);
                acc = fmaf(f4[0], e4[0], acc);
                acc = fmaf(f4[1], e4[1], acc);
                acc = fmaf(f4[2], e4[2], acc);
                acc = fmaf(f4[3], e4[3], acc);
            }
            int row = row0 + rl;
            float d = __fsub_rn(A[row], __fadd_rn(acc, acc));
            unsigned long long key =
                ((unsigned long long)__float_as_uint(d) << 32) | (unsigned)cand;
            atomicMin(&keys[row], key);
        }
        return;
    }

    for (int i = t; i < n; i += 256) {
        unsigned e = qBlk[i];
        int rl = (int)(e >> 13), cand = (int)(e & 8191u);
        const float* ep = emb + ((size_t)cand << 8);
        float acc = 0.f;
        #pragma unroll 8
        for (int c0 = 0; c0 < 256; c0 += 4) {
            f32x4 f4 = *(const f32x4*)&F[rl][c0];     // LDS, exact hs copy
            f32x4 e4 = *(const f32x4*)(ep + c0);      // global fp32 emb
            acc = fmaf(f4[0], e4[0], acc);
            acc = fmaf(f4[1], e4[1], acc);
            acc = fmaf(f4[2], e4[2], acc);
            acc = fmaf(f4[3], e4[3], acc);
        }
        int row = row0 + rl;
        float d = __fsub_rn(A[row], __fadd_rn(acc, acc));
        unsigned long long key =
            ((unsigned long long)__float_as_uint(d) << 32) | (unsigned)cand;
        atomicMin(&keys[row], key);
    }
}

// ---- kPost / kLoss (unchanged) ---------------------------------------------
__global__ void kPost(float* __restrict__ out) {
    const unsigned long long* keys = (const unsigned long long*)(out + SK_FLT);
    double* lossAcc = (double*)(out + SL_FLT);
    __shared__ double sd[256];
    int n = blockIdx.x * 256 + threadIdx.x;
    unsigned long long key = keys[n];
    unsigned idx = (unsigned)(key & 0xffffffffu) & 8191u;
    float d = __uint_as_float((unsigned)(key >> 32));
    out[NELEM + n] = (float)idx;
    sd[threadIdx.x] = (double)d;
    __syncthreads();
    for (int s = 128; s > 0; s >>= 1) {
        if (threadIdx.x < s) sd[threadIdx.x] += sd[threadIdx.x + s];
        __syncthreads();
    }
    if (threadIdx.x == 0) atomicAdd(lossAcc, sd[0]);
}

__global__ void kLoss(float* __restrict__ out) {
    if (threadIdx.x == 0) {
        double loss = 1.25 * (*(const double*)(out + SL_FLT)) / (double)NELEM;
        out[NELEM + N_ROWS] = (float)loss;
    }
}

// ---- kZQ: 64n x 64c LDS-tiled gather (r19) ---------------------------------
// grid 1024 = 256 nTile x 4 cTile. emb gathered 256B/row coalesced into
// E[c][n] (c-major -> conflict-free stage-3 reads); hs/z_q coalesced.
// Per-element formula byte-identical: out = fadd(h, fsub(e, h)).
__global__ __launch_bounds__(256) void kZQ(const float* __restrict__ hs,
                                           const float* __restrict__ emb,
                                           float* __restrict__ out) {
    __shared__ float E[64][65];           // [local c][local n]
    __shared__ unsigned idxL[64];

    const int t = threadIdx.x, blk = blockIdx.x;
    const int nt = blk >> 2, ct = blk & 3;
    const int row0 = nt * 64, c0 = ct * 64;
    const int b = row0 >> 10, yx0 = row0 & 1023;

    if (t < 64) idxL[t] = (unsigned)out[NELEM + row0 + t] & 8191u;
    __syncthreads();

    // gather: 4 threads/row, each reads 16 consecutive c (64B) -> LDS scatter
    {
        int r = t >> 2, j = t & 3;
        const float* ep = emb + ((size_t)idxL[r] << 8) + c0 + j * 16;
        #pragma unroll
        for (int q = 0; q < 4; ++q) {
            f32x4 v = *(const f32x4*)(ep + q * 4);
            #pragma unroll
            for (int i = 0; i < 4; ++i)
                E[j * 16 + q * 4 + i][r] = v[i];
        }
    }
    __syncthreads();

    // emit: thread (yl, ch): 16 c each; h read / z_q write coalesced
    {
        int yl = t & 63, ch = t >> 6;
        #pragma unroll
        for (int i = 0; i < 16; ++i) {
            int cl = ch * 16 + i;
            size_t o = ((size_t)b << 18) | ((size_t)(c0 + cl) << 10)
                     | (size_t)(yx0 + yl);
            float h = hs[o];
            float e = E[cl][yl];
            out[o] = __fadd_rn(h, __fsub_rn(e, h));
        }
    }
}

extern "C" void kernel_launch(void* const* d_in, const int* in_sizes, int n_in,
                              void* d_out, int out_size, void* d_ws, size_t ws_size,
                              hipStream_t stream) {
    const float* hs  = (const float*)d_in[0];
    const float* emb = (const float*)d_in[1];
    float* out = (float*)d_out;

    kA<<<N_ROWS / 256, 256, 0, stream>>>(hs, out);
    kFbf<<<1024, 256, 0, stream>>>(hs, out);
    kEbf<<<K_CAND / 256, 256, 0, stream>>>(emb, out);
    kScr<<<1024, 256, 0, stream>>>(hs, emb, out);
    kTailE<<<2048, 256, 0, stream>>>(hs, emb, out);
    kPost<<<N_ROWS / 256, 256, 0, stream>>>(out);
    kLoss<<<1, 64, 0, stream>>>(out);
    kZQ<<<1024, 256, 0, stream>>>(hs, emb, out);
}

// Round 10
// 349.146 us; speedup vs baseline: 1.1703x; 1.0021x over previous
//
#include <hip/hip_runtime.h>

// VectorQuantizer: N=16384 rows, C=256, K=8192. inputs fp32, outputs fp32
// (z_q 4194304 ++ indices 16384 ++ loss 1).
// r19 post-mortem: bneg-fold flat (kScr 139, pipes identical) -- scheduling
// knobs exhausted. Acting on the untouched counter: SQ_LDS_BANK_CONFLICT
// 8.1M/dispatch. As[.][264] row stride = 132 dw == 4 mod 32 -> the 16
// l15-lanes hit banks {0,4..28} and quad offset (4 dw) lands ON the same
// set => every A-frag ds_read_b128 is 8-way conflicted (~2.9x, on the MFMA
// critical path, ~2K cyc/wave).
// r20: fragment-linear A-tile As2: chunk D = m*512+(ks*4+quad)*16+l15, so
// the (m,ks) read is base + lane*16B = canonical conflict-free pattern
// (+ cheaper addressing). Staging writes become 32-way conflicted but run
// 8x once/block vs 128 reads/wave -- net win. Same bytes at same lanes =>
// MFMA inputs bit-identical. Also: kTailE F stride 260->264 (2-way max,
// 16B-aligned); kEbf regrid 32x256 -> 128x64 (was using 1/8 of CUs).
//
// margin_n = 2e-5*sqrt(A_n) + 4e-5; flag iff R~ + margin >= rowRunningMax
// (monotone LDS atomicMax, per 64-row x candSplit block; stale threshold
// only over-flags => safe). Exact path: F verbatim hs copy in LDS,
// sequential fmaf chain, u64 key tie-break -- byte-identical to r9-r19.
//
// Scratch in z_q float region of d_out (kZQ overwrites last); no d_ws.
// High-water 4,483,080 floats (= r14-r19's proven-safe envelope).

#define N_ROWS 16384
#define K_CAND 8192
#define CDIM   256
#define NELEM  4194304

#define SA_FLT   0          // A[16384] fp32 (numpy-pairwise-exact)
#define SK_FLT   16384      // keys u64[16384]
#define SL_FLT   49152      // lossAcc double
#define SQC_FLT  49160      // qcount u32[2048]
#define SBB_FLT  51208      // -B~ f32[8192]
#define SQ_FLT   59400      // queue u32[2048*624]
#define SFB_FLT  1337352    // fbf = bf16(2*f)[16384][256] as u16
#define SEB_FLT  3434504    // ebf2 = bf16(e) 16-cand panels (ends 4483080)
#define QCAP     624

typedef __attribute__((ext_vector_type(8))) short short8;
typedef __attribute__((ext_vector_type(4))) float f32x4;
typedef __attribute__((ext_vector_type(4))) unsigned uint32x4;

__device__ __forceinline__ unsigned short f2bf_rne(float x) {
    unsigned u = __float_as_uint(x);
    return (unsigned short)((u + 0x7fffu + ((u >> 16) & 1u)) >> 16);
}
__device__ __forceinline__ float bf2f(unsigned short u) {
    return __uint_as_float(((unsigned)u) << 16);
}
// monotone float->u32 map (handles negatives)
__device__ __forceinline__ unsigned ordU(float f) {
    unsigned u = __float_as_uint(f);
    return u ^ (((int)u >> 31) | 0x80000000u);
}

// ---- kA: numpy-pairwise-exact A[n]; init keys + loss -----------------------
__global__ void kA(const float* __restrict__ hs, float* __restrict__ out) {
    float* A = out + SA_FLT;
    unsigned long long* keys = (unsigned long long*)(out + SK_FLT);
    int n = blockIdx.x * 256 + threadIdx.x;
    keys[n] = ~0ull;
    if (n == 0) *(double*)(out + SL_FLT) = 0.0;
    int b = n >> 10, yx = n & 1023;
    const float* base = hs + ((size_t)b << 18) + yx;
    float hsum[2];
    for (int h = 0; h < 2; ++h) {
        float r[8];
        #pragma unroll
        for (int j = 0; j < 8; ++j) {
            float x = base[(size_t)(h * 128 + j) << 10];
            r[j] = __fmul_rn(x, x);
        }
        for (int i = 8; i < 128; i += 8) {
            #pragma unroll
            for (int j = 0; j < 8; ++j) {
                float x = base[(size_t)(h * 128 + i + j) << 10];
                r[j] = __fadd_rn(r[j], __fmul_rn(x, x));
            }
        }
        hsum[h] = __fadd_rn(
            __fadd_rn(__fadd_rn(r[0], r[1]), __fadd_rn(r[2], r[3])),
            __fadd_rn(__fadd_rn(r[4], r[5]), __fadd_rn(r[6], r[7])));
    }
    A[n] = __fadd_rn(hsum[0], hsum[1]);
}

// ---- kFbf: (b,c,yx) -> bf16(2*f)[n][c] via LDS transpose -------------------
__global__ void kFbf(const float* __restrict__ hs, float* __restrict__ out) {
    unsigned short* fbf = (unsigned short*)(out + SFB_FLT);
    __shared__ float T[64][65];
    int blk = blockIdx.x;                 // 16 b x 4 cBlk x 16 yBlk = 1024
    int b = blk >> 6, cB = (blk >> 4) & 3, yB = blk & 15;
    int t = threadIdx.x;
    int yl = t & 63, ch = t >> 6;
    const float* src = hs + ((size_t)b << 18) + (((size_t)cB * 64) << 10) + yB * 64 + yl;
    #pragma unroll
    for (int i = 0; i < 16; ++i) {
        int c = ch * 16 + i;
        T[c][yl] = src[(size_t)c << 10];
    }
    __syncthreads();
    int yr = t >> 2, cs = (t & 3) * 16;
    short8 v0, v1;
    #pragma unroll
    for (int j = 0; j < 8; ++j) {
        v0[j] = (short)f2bf_rne(2.0f * T[cs + j][yr]);
        v1[j] = (short)f2bf_rne(2.0f * T[cs + 8 + j][yr]);
    }
    unsigned short* dst = fbf + (((size_t)(b * 1024 + yB * 64 + yr)) << 8) + cB * 64 + cs;
    *(short8*)dst = v0;
    *(short8*)(dst + 8) = v1;
}

// ---- kEbf: bf16(e) -> 16-cand panel layout + (-B~) -------------------------
// ebf2 layout (shorts): g=cand>>4, kc=c0/8 (0..31), cl=cand&15:
//   addr = g*4096 + kc*128 + cl*8   (panel 8KB, chunk row 256B, 16B/cand)
// r20: grid 128 x 64 threads (was 32 x 256: only 1/8 of CUs active)
__global__ void kEbf(const float* __restrict__ emb, float* __restrict__ out) {
    unsigned short* ebf = (unsigned short*)(out + SEB_FLT);
    float* bbfNeg = out + SBB_FLT;
    int cand = blockIdx.x * 64 + threadIdx.x;
    const float* ep = emb + ((size_t)cand << 8);
    unsigned short* dp = ebf + (((size_t)(cand >> 4)) << 12) + (cand & 15) * 8;
    float s = 0.f;
    for (int c0 = 0; c0 < 256; c0 += 8) {
        short8 v;
        #pragma unroll
        for (int j = 0; j < 8; ++j) {
            unsigned short bb = f2bf_rne(ep[c0 + j]);
            v[j] = (short)bb;
            float eh = bf2f(bb);
            s = fmaf(eh, eh, s);
        }
        *(short8*)(dp + (c0 >> 3) * 128) = v;
    }
    bbfNeg[cand] = -s;
}

// ---- kScr: MFMA screen + flags -> per-half queues --------------------------
// grid 1024 = 256 rowBlk x 4 candSplit. acc[4][4] = 64 AGPR; cap 170.
// r20: fragment-linear A-tile: chunk D = m*512+(ks*4+quad)*16+l15 so the
// (m,ks) wave read = base + lane*16B (conflict-free, cheap addressing).
__global__ __launch_bounds__(256, 3) void kScr(const float* __restrict__ hs,
                                               const float* __restrict__ emb,
                                               float* __restrict__ out) {
    const float* A = out + SA_FLT;
    unsigned* qcount = (unsigned*)(out + SQC_FLT);
    const float* bbfNeg = out + SBB_FLT;
    unsigned* queue = (unsigned*)(out + SQ_FLT);
    const unsigned short* fbf = (const unsigned short*)(out + SFB_FLT);
    const unsigned short* ebf = (const unsigned short*)(out + SEB_FLT);

    __shared__ __align__(16) short As2[16384];    // fragment-linear A-tile
    __shared__ unsigned rowMaxOrd[64];
    __shared__ float margLds[64];
    __shared__ int lqnH[2];

    const int t = threadIdx.x, blk = blockIdx.x;
    const int row0 = (blk >> 2) * 64;
    const int candSplit = (blk & 3) * 2048;
    const int lane = t & 63, wid = t >> 6;
    const int quad = lane >> 4, l15 = lane & 15;
    // tail-block queue indices for the two 32-row halves:
    // qb = rowBlk32*4 + split, rowBlk32 = (blk>>2)*2 + h
    const int qb0 = (blk >> 2) * 8 + (blk & 3);
    unsigned* qB[2] = { queue + (size_t)qb0 * QCAP,
                        queue + (size_t)(qb0 + 4) * QCAP };

    if (t < 64) {
        rowMaxOrd[t] = 0u;
        margLds[t] = 2.0e-5f * sqrtf(A[row0 + t]) + 4.0e-5f;
    }
    if (t < 2) lqnH[t] = 0;

    // stage A-tile ONCE: coalesced 16-B global loads -> fragment-linear LDS.
    // src chunk d: row r = d>>5, 16B-chunk c32 = d&31 (32 chunks/row).
    // dst chunk D = (r>>4)*512 + c32*16 + (r&15)  [= m*512+(ks*4+quad)*16+l15]
    {
        const unsigned short* src = fbf + ((size_t)row0 << 8);
        #pragma unroll
        for (int i = 0; i < 8; ++i) {
            int d = i * 256 + t;
            short8 v = *(const short8*)(src + d * 8);
            int r = d >> 5, c32 = d & 31;
            int D = ((r >> 4) << 9) + (c32 << 4) + (r & 15);
            *(short8*)&As2[D << 3] = v;
        }
    }
    __syncthreads();     // the ONLY barrier before the final qcount store

    // loop-invariant margins -> registers (one batched LDS read per m)
    f32x4 mgv[4];
    #pragma unroll
    for (int m = 0; m < 4; ++m)
        mgv[m] = *(const f32x4*)&margLds[m * 16 + quad * 4];

    for (int cc = 0; cc < 8; ++cc) {
        const int candW = candSplit + cc * 256 + wid * 64;
        // per-wave panel base: lanes (quad,l15) -> contiguous 1KB per (jc,ks)
        const unsigned short* ebW = ebf + (((size_t)candW) << 8)
                                       + quad * 128 + l15 * 8;
        float bneg[4];
        #pragma unroll
        for (int jc = 0; jc < 4; ++jc)
            bneg[jc] = bbfNeg[candW + jc * 16 + l15];

        f32x4 acc[4][4];
        #pragma unroll
        for (int jc = 0; jc < 4; ++jc)
            #pragma unroll
            for (int m = 0; m < 4; ++m)
                acc[m][jc] = (f32x4){0.f, 0.f, 0.f, 0.f};
        #pragma unroll
        for (int ks = 0; ks < 8; ++ks) {
            short8 bf[4];
            #pragma unroll
            for (int jc = 0; jc < 4; ++jc)
                bf[jc] = *(const short8*)(ebW + jc * 4096 + ks * 512);
            #pragma unroll
            for (int m = 0; m < 4; ++m) {
                // conflict-free: lane reads base + lane*16B
                short8 af = *(const short8*)&As2[(((m * 8 + ks) << 6) + lane) << 3];
                #pragma unroll
                for (int jc = 0; jc < 4; ++jc)
                    acc[m][jc] = __builtin_amdgcn_mfma_f32_16x16x32_bf16(
                        af, bf[jc], acc[m][jc], 0, 0, 0);
            }
        }
        // flag: per-(m,reg) early-out; ballot consensus so the 16-lane
        // shuffle-max never runs with inactive lanes (garbage-max hazard).
        // x = acc + bneg (one fp32 add; folded from init).
        #pragma unroll
        for (int m = 0; m < 4; ++m) {
            uint32x4 thv = *(const uint32x4*)&rowMaxOrd[m * 16 + quad * 4];
            #pragma unroll
            for (int reg = 0; reg < 4; ++reg) {
                int rl = m * 16 + quad * 4 + reg;
                float x0 = __fadd_rn(acc[m][0][reg], bneg[0]);
                float x1 = __fadd_rn(acc[m][1][reg], bneg[1]);
                float x2 = __fadd_rn(acc[m][2][reg], bneg[2]);
                float x3 = __fadd_rn(acc[m][3][reg], bneg[3]);
                float vmax = fmaxf(fmaxf(x0, x1), fmaxf(x2, x3));
                unsigned th = thv[reg];
                float mg = mgv[m][reg];
                bool hot = ordU(__fadd_rn(vmax, mg)) >= th;
                unsigned long long bal = __ballot(hot);
                if (((bal >> (quad * 16)) & 0xFFFFull) == 0ull) continue;
                float g = vmax;                       // all 16 lanes active
                g = fmaxf(g, __shfl_xor(g, 1, 16));
                g = fmaxf(g, __shfl_xor(g, 2, 16));
                g = fmaxf(g, __shfl_xor(g, 4, 16));
                g = fmaxf(g, __shfl_xor(g, 8, 16));
                unsigned og = ordU(g);
                if (og > th) { atomicMax(&rowMaxOrd[rl], og); th = og; }
                float xs[4] = {x0, x1, x2, x3};
                #pragma unroll
                for (int jc = 0; jc < 4; ++jc) {
                    if (ordU(__fadd_rn(xs[jc], mg)) >= th) {
                        int slot = atomicAdd(&lqnH[m >> 1], 1);
                        if (slot < QCAP)
                            qB[m >> 1][slot] = ((unsigned)(rl & 31) << 13)
                                             | (unsigned)(candW + jc * 16 + l15);
                    }
                }
            }
        }
    }
    __syncthreads();
    if (t < 2) qcount[qb0 + t * 4] = (unsigned)lqnH[t];
}

// ---- kTailE: F-staged exact re-rank of queued candidates (+fallback) -------
// grid 2048, 32 rows/block. Exact chain byte-identical to r9-r19.
// r20: F stride 260 -> 264 floats (==8 mod 32 banks: 2-way max, 16B-aligned)
__global__ __launch_bounds__(256, 4) void kTailE(const float* __restrict__ hs,
                                                 const float* __restrict__ emb,
                                                 float* __restrict__ out) {
    const float* A = out + SA_FLT;
    unsigned long long* keys = (unsigned long long*)(out + SK_FLT);
    const unsigned* qcount = (const unsigned*)(out + SQC_FLT);
    const unsigned* queue = (const unsigned*)(out + SQ_FLT);

    __shared__ __align__(16) float F[32][264];

    const int t = threadIdx.x, blk = blockIdx.x;
    const int row0 = (blk >> 2) * 32;
    const unsigned* qBlk = queue + (size_t)blk * QCAP;

    int n = (int)qcount[blk];             // uniform read -> uniform branch
    if (n == 0) return;

    // stage block's 32 rows fp32 VERBATIM into LDS (coalesced: for fixed c,
    // 32 consecutive rows are contiguous in hs)
    {
        int yl = t & 31, cq = t >> 5;     // cq 0..7
        int nrow = row0 + yl;
        int b = nrow >> 10, yx = nrow & 1023;
        const float* src = hs + ((size_t)b << 18) + yx;
        #pragma unroll
        for (int i = 0; i < 32; ++i) {
            int c = i * 8 + cq;
            F[yl][c] = src[(size_t)c << 10];
        }
    }
    __syncthreads();

    if (n > QCAP) {                       // overflow: exact full scan (rare)
        int cb = (blk & 3) * 2048;
        for (int p = t; p < 32 * 2048; p += 256) {
            int rl = p >> 11, cand = cb + (p & 2047);
            const float* ep = emb + ((size_t)cand << 8);
            float acc = 0.f;
            #pragma unroll 8
            for (int c0 = 0; c0 < 256; c0 += 4) {
                f32x4 f4 = *(const f32x4*)&F[rl][c0];
                f32x4 e4 = *(const f32x4*)(ep + c0);
                acc = fmaf(f4[0], e4[0], acc);
                acc = fmaf(f4[1], e4[1], acc);
                acc = fmaf(f4[2], e4[2], acc);
                acc = fmaf(f4[3], e4[3], acc);
            }
            int row = row0 + rl;
            float d = __fsub_rn(A[row], __fadd_rn(acc, acc));
            unsigned long long key =
                ((unsigned long long)__float_as_uint(d) << 32) | (unsigned)cand;
            atomicMin(&keys[row], key);
        }
        return;
    }

    for (int i = t; i < n; i += 256) {
        unsigned e = qBlk[i];
        int rl = (int)(e >> 13), cand = (int)(e & 8191u);
        const float* ep = emb + ((size_t)cand << 8);
        float acc = 0.f;
        #pragma unroll 8
        for (int c0 = 0; c0 < 256; c0 += 4) {
            f32x4 f4 = *(const f32x4*)&F[rl][c0];     // LDS, exact hs copy
            f32x4 e4 = *(const f32x4*)(ep + c0);      // global fp32 emb
            acc = fmaf(f4[0], e4[0], acc);
            acc = fmaf(f4[1], e4[1], acc);
            acc = fmaf(f4[2], e4[2], acc);
            acc = fmaf(f4[3], e4[3], acc);
        }
        int row = row0 + rl;
        float d = __fsub_rn(A[row], __fadd_rn(acc, acc));
        unsigned long long key =
            ((unsigned long long)__float_as_uint(d) << 32) | (unsigned)cand;
        atomicMin(&keys[row], key);
    }
}

// ---- kPost / kLoss (unchanged) ---------------------------------------------
__global__ void kPost(float* __restrict__ out) {
    const unsigned long long* keys = (const unsigned long long*)(out + SK_FLT);
    double* lossAcc = (double*)(out + SL_FLT);
    __shared__ double sd[256];
    int n = blockIdx.x * 256 + threadIdx.x;
    unsigned long long key = keys[n];
    unsigned idx = (unsigned)(key & 0xffffffffu) & 8191u;
    float d = __uint_as_float((unsigned)(key >> 32));
    out[NELEM + n] = (float)idx;
    sd[threadIdx.x] = (double)d;
    __syncthreads();
    for (int s = 128; s > 0; s >>= 1) {
        if (threadIdx.x < s) sd[threadIdx.x] += sd[threadIdx.x + s];
        __syncthreads();
    }
    if (threadIdx.x == 0) atomicAdd(lossAcc, sd[0]);
}

__global__ void kLoss(float* __restrict__ out) {
    if (threadIdx.x == 0) {
        double loss = 1.25 * (*(const double*)(out + SL_FLT)) / (double)NELEM;
        out[NELEM + N_ROWS] = (float)loss;
    }
}

// ---- kZQ: 64n x 64c LDS-tiled gather (r19, unchanged) ----------------------
__global__ __launch_bounds__(256) void kZQ(const float* __restrict__ hs,
                                           const float* __restrict__ emb,
                                           float* __restrict__ out) {
    __shared__ float E[64][65];           // [local c][local n]
    __shared__ unsigned idxL[64];

    const int t = threadIdx.x, blk = blockIdx.x;
    const int nt = blk >> 2, ct = blk & 3;
    const int row0 = nt * 64, c0 = ct * 64;
    const int b = row0 >> 10, yx0 = row0 & 1023;

    if (t < 64) idxL[t] = (unsigned)out[NELEM + row0 + t] & 8191u;
    __syncthreads();

    // gather: 4 threads/row, each reads 16 consecutive c (64B) -> LDS scatter
    {
        int r = t >> 2, j = t & 3;
        const float* ep = emb + ((size_t)idxL[r] << 8) + c0 + j * 16;
        #pragma unroll
        for (int q = 0; q < 4; ++q) {
            f32x4 v = *(const f32x4*)(ep + q * 4);
            #pragma unroll
            for (int i = 0; i < 4; ++i)
                E[j * 16 + q * 4 + i][r] = v[i];
        }
    }
    __syncthreads();

    // emit: thread (yl, ch): 16 c each; h read / z_q write coalesced
    {
        int yl = t & 63, ch = t >> 6;
        #pragma unroll
        for (int i = 0; i < 16; ++i) {
            int cl = ch * 16 + i;
            size_t o = ((size_t)b << 18) | ((size_t)(c0 + cl) << 10)
                     | (size_t)(yx0 + yl);
            float h = hs[o];
            float e = E[cl][yl];
            out[o] = __fadd_rn(h, __fsub_rn(e, h));
        }
    }
}

extern "C" void kernel_launch(void* const* d_in, const int* in_sizes, int n_in,
                              void* d_out, int out_size, void* d_ws, size_t ws_size,
                              hipStream_t stream) {
    const float* hs  = (const float*)d_in[0];
    const float* emb = (const float*)d_in[1];
    float* out = (float*)d_out;

    kA<<<N_ROWS / 256, 256, 0, stream>>>(hs, out);
    kFbf<<<1024, 256, 0, stream>>>(hs, out);
    kEbf<<<K_CAND / 64, 64, 0, stream>>>(emb, out);
    kScr<<<1024, 256, 0, stream>>>(hs, emb, out);
    kTailE<<<2048, 256, 0, stream>>>(hs, emb, out);
    kPost<<<N_ROWS / 256, 256, 0, stream>>>(out);
    kLoss<<<1, 64, 0, stream>>>(out);
    kZQ<<<1024, 256, 0, stream>>>(hs, emb, out);
}

// Round 11
// 302.754 us; speedup vs baseline: 1.3497x; 1.1532x over previous
//
#include <hip/hip_runtime.h>

// VectorQuantizer: N=16384 rows, C=256, K=8192. inputs fp32, outputs fp32
// (z_q 4194304 ++ indices 16384 ++ loss 1).
// r20: A-frag conflicts eliminated (8.1M->5.75M) but kScr FLAT at 138 ->
// LDS not critical path; kScr parked after 4 flat rounds. The unprofiled
// 211us aux side has memory floors <40us -> launch gaps + redundancy.
// r21: consolidation. 8->6 launches, 3->2 hs passes, tail staging 4x->1x:
//   kAF  = kA + kFbf fused (one 32rx256c LDS tile feeds bf16 transpose AND
//          exact A-chain; h-halves on paired lanes + shfl_down(32), ops
//          byte-identical to kA). keys/loss init moved here.
//   kTailM = 4 candSplit tails merged per 32-row group: stage F ONCE,
//          drain queues R*4+s (mapping verified vs kScr's (blk>>2)*8+s+h*4).
//   kZQf = kPost + kZQ fused: idx from keys; ct==0 writes indices + wave-
//          reduced loss partial (double regroup error ~4e-12 << float ulp).
//   kScr: staging-write swizzle D^=(D>>4)&7 BOTH sides (write 32->4-way;
//          read stays contiguous-1KB permutation via precomputed off0/off1).
//
// margin_n = 2e-5*sqrt(A_n) + 4e-5; flag iff R~ + margin >= rowRunningMax
// (monotone LDS atomicMax, per 64-row x candSplit block; stale threshold
// only over-flags => safe). Exact path: F verbatim hs copy in LDS,
// sequential fmaf chain, u64 key tie-break -- byte-identical to r9-r20.
//
// Scratch in z_q float region of d_out (kZQf overwrites last); no d_ws.
// High-water 4,483,080 floats (= r14-r20's proven-safe envelope).

#define N_ROWS 16384
#define K_CAND 8192
#define CDIM   256
#define NELEM  4194304

#define SA_FLT   0          // A[16384] fp32 (numpy-pairwise-exact)
#define SK_FLT   16384      // keys u64[16384]
#define SL_FLT   49152      // lossAcc double
#define SQC_FLT  49160      // qcount u32[2048]
#define SBB_FLT  51208      // -B~ f32[8192]
#define SQ_FLT   59400      // queue u32[2048*624]
#define SFB_FLT  1337352    // fbf = bf16(2*f)[16384][256] as u16
#define SEB_FLT  3434504    // ebf2 = bf16(e) 16-cand panels (ends 4483080)
#define QCAP     624

typedef __attribute__((ext_vector_type(8))) short short8;
typedef __attribute__((ext_vector_type(4))) float f32x4;
typedef __attribute__((ext_vector_type(4))) unsigned uint32x4;

__device__ __forceinline__ unsigned short f2bf_rne(float x) {
    unsigned u = __float_as_uint(x);
    return (unsigned short)((u + 0x7fffu + ((u >> 16) & 1u)) >> 16);
}
__device__ __forceinline__ float bf2f(unsigned short u) {
    return __uint_as_float(((unsigned)u) << 16);
}
// monotone float->u32 map (handles negatives)
__device__ __forceinline__ unsigned ordU(float f) {
    unsigned u = __float_as_uint(f);
    return u ^ (((int)u >> 31) | 0x80000000u);
}

// ---- kAF: fused kA + kFbf (one hs pass) + keys/loss init -------------------
// grid 512 = 16 b x 32 yB; 32 rows x 256 c per block.
__global__ __launch_bounds__(256) void kAF(const float* __restrict__ hs,
                                           float* __restrict__ out) {
    float* A = out + SA_FLT;
    unsigned long long* keys = (unsigned long long*)(out + SK_FLT);
    unsigned short* fbf = (unsigned short*)(out + SFB_FLT);
    __shared__ float T[256][33];

    const int t = threadIdx.x, blk = blockIdx.x;
    const int b = blk >> 5, yB = blk & 31;
    const int row0 = b * 1024 + yB * 32;
    if (blk == 0 && t == 0) *(double*)(out + SL_FLT) = 0.0;
    if (t < 32) keys[row0 + t] = ~0ull;

    // stage 32 rows x 256 c fp32 VERBATIM (coalesced per 32-lane group)
    {
        int yl = t & 31, ch = t >> 5;     // ch 0..7
        const float* src = hs + ((size_t)b << 18) + yB * 32 + yl;
        #pragma unroll
        for (int i = 0; i < 32; ++i) {
            int c = i * 8 + ch;
            T[c][yl] = src[(size_t)c << 10];
        }
    }
    __syncthreads();

    // A-chain: wave 0 only; lane = yl + h*32. Ops identical to old kA:
    // per-h r[8] stripes, pairwise combine, then fadd(hsum0, hsum1).
    if (t < 64) {
        int yl = t & 31, h = t >> 5;
        float r[8];
        #pragma unroll
        for (int j = 0; j < 8; ++j) {
            float x = T[h * 128 + j][yl];
            r[j] = __fmul_rn(x, x);
        }
        for (int i = 8; i < 128; i += 8) {
            #pragma unroll
            for (int j = 0; j < 8; ++j) {
                float x = T[h * 128 + i + j][yl];
                r[j] = __fadd_rn(r[j], __fmul_rn(x, x));
            }
        }
        float hsum = __fadd_rn(
            __fadd_rn(__fadd_rn(r[0], r[1]), __fadd_rn(r[2], r[3])),
            __fadd_rn(__fadd_rn(r[4], r[5]), __fadd_rn(r[6], r[7])));
        float other = __shfl_down(hsum, 32);   // h=1 partner's hsum
        if (h == 0) A[row0 + yl] = __fadd_rn(hsum, other);
    }

    // fbf transpose: all threads; thread (yl, cq) emits 32 c of its row
    {
        int yl = t & 31, cq = t >> 5;
        unsigned short* dst = fbf + (((size_t)(row0 + yl)) << 8) + cq * 32;
        #pragma unroll
        for (int v = 0; v < 4; ++v) {
            short8 w;
            #pragma unroll
            for (int j = 0; j < 8; ++j)
                w[j] = (short)f2bf_rne(2.0f * T[cq * 32 + v * 8 + j][yl]);
            *(short8*)(dst + v * 8) = w;
        }
    }
}

// ---- kEbf: bf16(e) -> 16-cand panel layout + (-B~) -------------------------
// ebf2 layout (shorts): g=cand>>4, kc=c0/8 (0..31), cl=cand&15:
//   addr = g*4096 + kc*128 + cl*8   (panel 8KB, chunk row 256B, 16B/cand)
__global__ void kEbf(const float* __restrict__ emb, float* __restrict__ out) {
    unsigned short* ebf = (unsigned short*)(out + SEB_FLT);
    float* bbfNeg = out + SBB_FLT;
    int cand = blockIdx.x * 64 + threadIdx.x;     // grid 128 x 64
    const float* ep = emb + ((size_t)cand << 8);
    unsigned short* dp = ebf + (((size_t)(cand >> 4)) << 12) + (cand & 15) * 8;
    float s = 0.f;
    for (int c0 = 0; c0 < 256; c0 += 8) {
        short8 v;
        #pragma unroll
        for (int j = 0; j < 8; ++j) {
            unsigned short bb = f2bf_rne(ep[c0 + j]);
            v[j] = (short)bb;
            float eh = bf2f(bb);
            s = fmaf(eh, eh, s);
        }
        *(short8*)(dp + (c0 >> 3) * 128) = v;
    }
    bbfNeg[cand] = -s;
}

// ---- kScr: MFMA screen + flags -> per-half queues --------------------------
// grid 1024 = 256 rowBlk x 4 candSplit. acc[4][4] = 64 AGPR; cap 170.
// r21: fragment-linear A-tile with XOR swizzle D^=(D>>4)&7 on BOTH sides:
// writes spread 32->4-way; reads remain a contiguous-1KB permutation
// (conflict-free) selected via precomputed off0/off1 (zero loop VALU).
__global__ __launch_bounds__(256, 3) void kScr(const float* __restrict__ hs,
                                               const float* __restrict__ emb,
                                               float* __restrict__ out) {
    const float* A = out + SA_FLT;
    unsigned* qcount = (unsigned*)(out + SQC_FLT);
    const float* bbfNeg = out + SBB_FLT;
    unsigned* queue = (unsigned*)(out + SQ_FLT);
    const unsigned short* fbf = (const unsigned short*)(out + SFB_FLT);
    const unsigned short* ebf = (const unsigned short*)(out + SEB_FLT);

    __shared__ __align__(16) short As2[16384];    // fragment-linear A-tile
    __shared__ unsigned rowMaxOrd[64];
    __shared__ float margLds[64];
    __shared__ int lqnH[2];

    const int t = threadIdx.x, blk = blockIdx.x;
    const int row0 = (blk >> 2) * 64;
    const int candSplit = (blk & 3) * 2048;
    const int lane = t & 63, wid = t >> 6;
    const int quad = lane >> 4, l15 = lane & 15;
    const int qb0 = (blk >> 2) * 8 + (blk & 3);
    unsigned* qB[2] = { queue + (size_t)qb0 * QCAP,
                        queue + (size_t)(qb0 + 4) * QCAP };

    if (t < 64) {
        rowMaxOrd[t] = 0u;
        margLds[t] = 2.0e-5f * sqrtf(A[row0 + t]) + 4.0e-5f;
    }
    if (t < 2) lqnH[t] = 0;

    // stage A-tile ONCE, swizzled fragment-linear:
    // canonical chunk D = (r>>4)*512 + c32*16 + (r&15); store at D^(c32&7).
    {
        const unsigned short* src = fbf + ((size_t)row0 << 8);
        #pragma unroll
        for (int i = 0; i < 8; ++i) {
            int d = i * 256 + t;
            short8 v = *(const short8*)(src + d * 8);
            int r = d >> 5, c32 = d & 31;
            int D = ((r >> 4) << 9) + (c32 << 4) + (r & 15);
            D ^= (c32 & 7);
            *(short8*)&As2[D << 3] = v;
        }
    }
    __syncthreads();     // the ONLY barrier before the final qcount store

    // read-side swizzled offsets (shorts): even ks -> off0, odd ks -> off1
    const int off0 = ((quad << 4) + (l15 ^ quad)) << 3;
    const int off1 = ((quad << 4) + (l15 ^ quad ^ 4)) << 3;

    // loop-invariant margins -> registers (one batched LDS read per m)
    f32x4 mgv[4];
    #pragma unroll
    for (int m = 0; m < 4; ++m)
        mgv[m] = *(const f32x4*)&margLds[m * 16 + quad * 4];

    for (int cc = 0; cc < 8; ++cc) {
        const int candW = candSplit + cc * 256 + wid * 64;
        const unsigned short* ebW = ebf + (((size_t)candW) << 8)
                                       + quad * 128 + l15 * 8;
        float bneg[4];
        #pragma unroll
        for (int jc = 0; jc < 4; ++jc)
            bneg[jc] = bbfNeg[candW + jc * 16 + l15];

        f32x4 acc[4][4];
        #pragma unroll
        for (int jc = 0; jc < 4; ++jc)
            #pragma unroll
            for (int m = 0; m < 4; ++m)
                acc[m][jc] = (f32x4){0.f, 0.f, 0.f, 0.f};
        #pragma unroll
        for (int ks = 0; ks < 8; ++ks) {
            short8 bf[4];
            #pragma unroll
            for (int jc = 0; jc < 4; ++jc)
                bf[jc] = *(const short8*)(ebW + jc * 4096 + ks * 512);
            #pragma unroll
            for (int m = 0; m < 4; ++m) {
                short8 af = *(const short8*)&As2[((m * 8 + ks) << 9)
                                                 + ((ks & 1) ? off1 : off0)];
                #pragma unroll
                for (int jc = 0; jc < 4; ++jc)
                    acc[m][jc] = __builtin_amdgcn_mfma_f32_16x16x32_bf16(
                        af, bf[jc], acc[m][jc], 0, 0, 0);
            }
        }
        // flag: per-(m,reg) early-out; ballot consensus so the 16-lane
        // shuffle-max never runs with inactive lanes (garbage-max hazard).
        #pragma unroll
        for (int m = 0; m < 4; ++m) {
            uint32x4 thv = *(const uint32x4*)&rowMaxOrd[m * 16 + quad * 4];
            #pragma unroll
            for (int reg = 0; reg < 4; ++reg) {
                int rl = m * 16 + quad * 4 + reg;
                float x0 = __fadd_rn(acc[m][0][reg], bneg[0]);
                float x1 = __fadd_rn(acc[m][1][reg], bneg[1]);
                float x2 = __fadd_rn(acc[m][2][reg], bneg[2]);
                float x3 = __fadd_rn(acc[m][3][reg], bneg[3]);
                float vmax = fmaxf(fmaxf(x0, x1), fmaxf(x2, x3));
                unsigned th = thv[reg];
                float mg = mgv[m][reg];
                bool hot = ordU(__fadd_rn(vmax, mg)) >= th;
                unsigned long long bal = __ballot(hot);
                if (((bal >> (quad * 16)) & 0xFFFFull) == 0ull) continue;
                float g = vmax;                       // all 16 lanes active
                g = fmaxf(g, __shfl_xor(g, 1, 16));
                g = fmaxf(g, __shfl_xor(g, 2, 16));
                g = fmaxf(g, __shfl_xor(g, 4, 16));
                g = fmaxf(g, __shfl_xor(g, 8, 16));
                unsigned og = ordU(g);
                if (og > th) { atomicMax(&rowMaxOrd[rl], og); th = og; }
                float xs[4] = {x0, x1, x2, x3};
                #pragma unroll
                for (int jc = 0; jc < 4; ++jc) {
                    if (ordU(__fadd_rn(xs[jc], mg)) >= th) {
                        int slot = atomicAdd(&lqnH[m >> 1], 1);
                        if (slot < QCAP)
                            qB[m >> 1][slot] = ((unsigned)(rl & 31) << 13)
                                             | (unsigned)(candW + jc * 16 + l15);
                    }
                }
            }
        }
    }
    __syncthreads();
    if (t < 2) qcount[qb0 + t * 4] = (unsigned)lqnH[t];
}

// ---- kTailM: merged tail -- stage F once, drain 4 candSplit queues ---------
// grid 512 (one block per 32-row group). Queues at R*4+s. Exact chain
// byte-identical to r9-r20.
__global__ __launch_bounds__(256, 4) void kTailM(const float* __restrict__ hs,
                                                 const float* __restrict__ emb,
                                                 float* __restrict__ out) {
    const float* A = out + SA_FLT;
    unsigned long long* keys = (unsigned long long*)(out + SK_FLT);
    const unsigned* qcount = (const unsigned*)(out + SQC_FLT);
    const unsigned* queue = (const unsigned*)(out + SQ_FLT);

    __shared__ __align__(16) float F[32][264];

    const int t = threadIdx.x, R = blockIdx.x;
    const int row0 = R * 32;

    int nq[4];
    #pragma unroll
    for (int s = 0; s < 4; ++s) nq[s] = (int)qcount[R * 4 + s];
    if ((nq[0] | nq[1] | nq[2] | nq[3]) == 0) return;

    // stage 32 rows fp32 VERBATIM into LDS (once, not 4x)
    {
        int yl = t & 31, cq = t >> 5;
        int nrow = row0 + yl;
        int b = nrow >> 10, yx = nrow & 1023;
        const float* src = hs + ((size_t)b << 18) + yx;
        #pragma unroll
        for (int i = 0; i < 32; ++i) {
            int c = i * 8 + cq;
            F[yl][c] = src[(size_t)c << 10];
        }
    }
    __syncthreads();

    for (int s = 0; s < 4; ++s) {
        int n = nq[s];
        if (n == 0) continue;
        if (n > QCAP) {                   // overflow: full scan of split s
            int cb = s * 2048;
            for (int p = t; p < 32 * 2048; p += 256) {
                int rl = p >> 11, cand = cb + (p & 2047);
                const float* ep = emb + ((size_t)cand << 8);
                float acc = 0.f;
                #pragma unroll 8
                for (int c0 = 0; c0 < 256; c0 += 4) {
                    f32x4 f4 = *(const f32x4*)&F[rl][c0];
                    f32x4 e4 = *(const f32x4*)(ep + c0);
                    acc = fmaf(f4[0], e4[0], acc);
                    acc = fmaf(f4[1], e4[1], acc);
                    acc = fmaf(f4[2], e4[2], acc);
                    acc = fmaf(f4[3], e4[3], acc);
                }
                int row = row0 + rl;
                float d = __fsub_rn(A[row], __fadd_rn(acc, acc));
                unsigned long long key =
                    ((unsigned long long)__float_as_uint(d) << 32) | (unsigned)cand;
                atomicMin(&keys[row], key);
            }
            continue;
        }
        const unsigned* qBlk = queue + (size_t)(R * 4 + s) * QCAP;
        for (int i = t; i < n; i += 256) {
            unsigned e = qBlk[i];
            int rl = (int)(e >> 13), cand = (int)(e & 8191u);
            const float* ep = emb + ((size_t)cand << 8);
            float acc = 0.f;
            #pragma unroll 8
            for (int c0 = 0; c0 < 256; c0 += 4) {
                f32x4 f4 = *(const f32x4*)&F[rl][c0];     // LDS, exact hs copy
                f32x4 e4 = *(const f32x4*)(ep + c0);      // global fp32 emb
                acc = fmaf(f4[0], e4[0], acc);
                acc = fmaf(f4[1], e4[1], acc);
                acc = fmaf(f4[2], e4[2], acc);
                acc = fmaf(f4[3], e4[3], acc);
            }
            int row = row0 + rl;
            float d = __fsub_rn(A[row], __fadd_rn(acc, acc));
            unsigned long long key =
                ((unsigned long long)__float_as_uint(d) << 32) | (unsigned)cand;
            atomicMin(&keys[row], key);
        }
    }
}

// ---- kZQf: fused kPost + kZQ -----------------------------------------------
// grid 1024 = 256 nTile x 4 cTile. idx from keys; ct==0 writes indices +
// wave-reduced loss partial (double regrouping error << float ulp of loss).
__global__ __launch_bounds__(256) void kZQf(const float* __restrict__ hs,
                                            const float* __restrict__ emb,
                                            float* __restrict__ out) {
    const unsigned long long* keys = (const unsigned long long*)(out + SK_FLT);
    __shared__ float E[64][65];           // [local c][local n]
    __shared__ unsigned idxL[64];

    const int t = threadIdx.x, blk = blockIdx.x;
    const int nt = blk >> 2, ct = blk & 3;
    const int row0 = nt * 64, c0 = ct * 64;
    const int b = row0 >> 10, yx0 = row0 & 1023;

    if (t < 64) {
        unsigned long long key = keys[row0 + t];
        unsigned idx = (unsigned)key & 8191u;
        idxL[t] = idx;
        if (ct == 0) {
            out[NELEM + row0 + t] = (float)idx;
            double d = (double)__uint_as_float((unsigned)(key >> 32));
            d += __shfl_down(d, 32);
            d += __shfl_down(d, 16);
            d += __shfl_down(d, 8);
            d += __shfl_down(d, 4);
            d += __shfl_down(d, 2);
            d += __shfl_down(d, 1);
            if (t == 0) atomicAdd((double*)(out + SL_FLT), d);
        }
    }
    __syncthreads();

    // gather: 4 threads/row, each reads 16 consecutive c (64B) -> LDS scatter
    {
        int r = t >> 2, j = t & 3;
        const float* ep = emb + ((size_t)idxL[r] << 8) + c0 + j * 16;
        #pragma unroll
        for (int q = 0; q < 4; ++q) {
            f32x4 v = *(const f32x4*)(ep + q * 4);
            #pragma unroll
            for (int i = 0; i < 4; ++i)
                E[j * 16 + q * 4 + i][r] = v[i];
        }
    }
    __syncthreads();

    // emit: thread (yl, ch): 16 c each; h read / z_q write coalesced
    {
        int yl = t & 63, ch = t >> 6;
        #pragma unroll
        for (int i = 0; i < 16; ++i) {
            int cl = ch * 16 + i;
            size_t o = ((size_t)b << 18) | ((size_t)(c0 + cl) << 10)
                     | (size_t)(yx0 + yl);
            float h = hs[o];
            float e = E[cl][yl];
            out[o] = __fadd_rn(h, __fsub_rn(e, h));
        }
    }
}

__global__ void kLoss(float* __restrict__ out) {
    if (threadIdx.x == 0) {
        double loss = 1.25 * (*(const double*)(out + SL_FLT)) / (double)NELEM;
        out[NELEM + N_ROWS] = (float)loss;
    }
}

extern "C" void kernel_launch(void* const* d_in, const int* in_sizes, int n_in,
                              void* d_out, int out_size, void* d_ws, size_t ws_size,
                              hipStream_t stream) {
    const float* hs  = (const float*)d_in[0];
    const float* emb = (const float*)d_in[1];
    float* out = (float*)d_out;

    kAF<<<512, 256, 0, stream>>>(hs, out);
    kEbf<<<K_CAND / 64, 64, 0, stream>>>(emb, out);
    kScr<<<1024, 256, 0, stream>>>(hs, emb, out);
    kTailM<<<512, 256, 0, stream>>>(hs, emb, out);
    kZQf<<<1024, 256, 0, stream>>>(hs, emb, out);
    kLoss<<<1, 64, 0, stream>>>(out);
}